// Round 9
// baseline (399.537 us; speedup 1.0000x reference)
//
#include <hip/hip_runtime.h>
#include <hip/hip_bf16.h>
#include <math.h>

#define NN 50000
#define NE 400000

typedef __attribute__((ext_vector_type(8))) short bf16x8;
typedef __attribute__((ext_vector_type(4))) float f32x4;

// ---------------- helpers ----------------
__device__ __forceinline__ float lrelu(float v){ return v > 0.f ? v : 0.2f*v; }
__device__ __forceinline__ float elu1(float v){ return v > 0.f ? v : expm1f(v); }
__device__ __forceinline__ float bflo(unsigned int u){ return __uint_as_float(u << 16); }
__device__ __forceinline__ float bfhi(unsigned int u){ return __uint_as_float(u & 0xffff0000u); }
__device__ __forceinline__ unsigned short f2bf(float f){
  __hip_bfloat16 h = __float2bfloat16(f);
  return *(unsigned short*)&h;
}
__device__ __forceinline__ unsigned int pack2(float lo, float hi){
  return (unsigned int)f2bf(lo) | ((unsigned int)f2bf(hi) << 16);
}

// ---------------- CSR build ----------------
__global__ void k_count(const int* __restrict__ col, int* __restrict__ cnt, int E){
  int e = blockIdx.x*blockDim.x + threadIdx.x;
  if(e < E) atomicAdd(&cnt[col[e]], 1);
}

__global__ void k_alloc(const int* __restrict__ cnt, int* __restrict__ offs,
                        float* __restrict__ dis, float* __restrict__ invc,
                        int* __restrict__ total, int N){
  int i = blockIdx.x*blockDim.x + threadIdx.x;
  int lane = threadIdx.x & 63;
  int v = (i < N) ? cnt[i] : 0;
  int x = v;
  #pragma unroll
  for(int d = 1; d < 64; d <<= 1){ int t = __shfl_up(x, d, 64); if(lane >= d) x += t; }
  int base = 0;
  if(lane == 63 && x > 0) base = atomicAdd(total, x);
  base = __shfl(base, 63, 64);
  if(i < N){
    offs[i] = base + x - v;
    dis[i]  = 1.0f / sqrtf((float)(v + 1));
    invc[i] = 1.0f / fmaxf((float)v, 1.0f);
  }
}

__global__ void k_fill(const int* __restrict__ row, const int* __restrict__ col,
                       const int* __restrict__ offs, int* __restrict__ cursor,
                       int* __restrict__ csr, int E){
  int e = blockIdx.x*blockDim.x + threadIdx.x;
  if(e < E){
    int c = col[e];
    int pos = offs[c] + atomicAdd(&cursor[c], 1);
    csr[pos] = row[e];
  }
}

// ---------------- pack weights -> bf16 transposed WT[col][k] ----------------
struct PKE { const float* W; unsigned short* T; int C, K; };
struct PKP { PKE e[8]; };
__global__ void k_pack(PKP p){
  PKE m = p.e[blockIdx.x];
  int total = m.C * m.K;
  for(int i = threadIdx.x; i < total; i += 256){
    int c = i / m.K, k = i - c*m.K;
    m.T[i] = f2bf(m.W[(size_t)k*m.C + c]);
  }
}

// ---------------- cast x -> bf16 + column sums for gate ----------------
__global__ void k_castsum(const float* __restrict__ x, unsigned short* __restrict__ xb,
                          float* __restrict__ gsum, int N){
  __shared__ float part[4][64];
  int lane = threadIdx.x & 63, w = threadIdx.x >> 6;
  float s = 0.f;
  for(int r = blockIdx.x*4 + w; r < N; r += gridDim.x*4){
    float v = x[(size_t)r*64 + lane];
    xb[(size_t)r*64 + lane] = f2bf(v);
    s += v;
  }
  part[w][lane] = s;
  __syncthreads();
  if(w == 0) atomicAdd(&gsum[lane], part[0][lane]+part[1][lane]+part[2][lane]+part[3][lane]);
}

__global__ void k_gate(const float* __restrict__ gsum,
                       const float* __restrict__ w1, const float* __restrict__ b1,
                       const float* __restrict__ w2, const float* __restrict__ b2,
                       float* __restrict__ gatew){
  __shared__ float g[64]; __shared__ float hid[64]; __shared__ float lg[3];
  int t = threadIdx.x;
  g[t] = gsum[t] * (1.0f/(float)NN);
  __syncthreads();
  float acc = b1[t];
  for(int i = 0; i < 64; i++) acc += g[i]*w1[i*64 + t];
  hid[t] = fmaxf(acc, 0.f);
  __syncthreads();
  if(t < 3){
    float a = b2[t];
    for(int j = 0; j < 64; j++) a += hid[j]*w2[j*3 + t];
    lg[t] = a;
  }
  __syncthreads();
  if(t == 0){
    float m = fmaxf(lg[0], fmaxf(lg[1], lg[2]));
    float e0 = expf(lg[0]-m), e1 = expf(lg[1]-m), e2 = expf(lg[2]-m);
    float s = e0 + e1 + e2;
    gatew[0] = e0/s; gatew[1] = e1/s; gatew[2] = e2/s;
  }
}

// ---------------- fold GAT1 attention vectors through W ----------------
__global__ void k_fold1(const float* __restrict__ w1, const float* __restrict__ as,
                        const float* __restrict__ ad, float* __restrict__ wsd){
  int t = threadIdx.x;            // 256
  int k = t & 63, h = t >> 6;
  float ssrc = 0.f, sdst = 0.f;
  for(int c = 0; c < 64; c++){
    float w = w1[k*256 + h*64 + c];
    ssrc += w * as[h*64 + c];
    sdst += w * ad[h*64 + c];
  }
  wsd[k*8 + h] = ssrc;
  wsd[k*8 + 4 + h] = sdst;
}

// ---------------- asrc1/adst1 = xb @ Wsd  (16 lanes per node) ----------------
__global__ void k_attdotx(const unsigned short* __restrict__ xb, const float* __restrict__ wsd,
                          float* __restrict__ asrc, float* __restrict__ adst, int N){
  __shared__ float ws[64*8];
  int tid = threadIdx.x;
  ws[tid] = wsd[tid];
  ws[tid + 256] = wsd[tid + 256];
  __syncthreads();
  int node = blockIdx.x*16 + (tid >> 4);
  int l = tid & 15;
  if(node >= N) return;
  uint2 u = *(const uint2*)&xb[(size_t)node*64 + l*4];
  float v0 = bflo(u.x), v1 = bfhi(u.x), v2 = bflo(u.y), v3 = bfhi(u.y);
  float s[8];
  #pragma unroll
  for(int h = 0; h < 8; h++){
    s[h] = v0*ws[(l*4+0)*8+h] + v1*ws[(l*4+1)*8+h] + v2*ws[(l*4+2)*8+h] + v3*ws[(l*4+3)*8+h];
  }
  #pragma unroll
  for(int d = 8; d >= 1; d >>= 1){
    #pragma unroll
    for(int h = 0; h < 8; h++) s[h] += __shfl_xor(s[h], d, 16);
  }
  if(l == 0){
    float4 o1; o1.x = s[0]; o1.y = s[1]; o1.z = s[2]; o1.w = s[3];
    float4 o2; o2.x = s[4]; o2.y = s[5]; o2.z = s[6]; o2.w = s[7];
    *(float4*)&asrc[node*4] = o1;
    *(float4*)&adst[node*4] = o2;
  }
}

// ---------------- GAT edge weights ----------------
__global__ void k_edgew1(const float* __restrict__ asrc, const float* __restrict__ adst,
                         const int* __restrict__ offs, const int* __restrict__ cnt,
                         const int* __restrict__ csr,
                         float* __restrict__ wvE, float* __restrict__ rdenN,
                         float* __restrict__ wvS, int N){
  int node = blockIdx.x*4 + (threadIdx.x >> 6);
  int lane = threadIdx.x & 63;
  if(node >= N) return;
  float4 ad = *(const float4*)&adst[node*4];
  float a0 = 0.f, a1 = 0.f, a2 = 0.f, a3 = 0.f;
  int e0 = offs[node], e1 = e0 + cnt[node];
  for(int e = e0 + lane; e < e1; e += 64){
    int s = csr[e];
    float4 as = *(const float4*)&asrc[s*4];
    float4 w;
    w.x = expf(lrelu(as.x + ad.x));
    w.y = expf(lrelu(as.y + ad.y));
    w.z = expf(lrelu(as.z + ad.z));
    w.w = expf(lrelu(as.w + ad.w));
    a0 += w.x; a1 += w.y; a2 += w.z; a3 += w.w;
    *(float4*)&wvE[(size_t)e*4] = w;
  }
  #pragma unroll
  for(int d = 32; d >= 1; d >>= 1){
    a0 += __shfl_xor(a0, d, 64); a1 += __shfl_xor(a1, d, 64);
    a2 += __shfl_xor(a2, d, 64); a3 += __shfl_xor(a3, d, 64);
  }
  float4 asl = *(const float4*)&asrc[node*4];
  float4 ws;
  ws.x = expf(lrelu(asl.x + ad.x));
  ws.y = expf(lrelu(asl.y + ad.y));
  ws.z = expf(lrelu(asl.z + ad.z));
  ws.w = expf(lrelu(asl.w + ad.w));
  if(lane == 0){
    float4 rd;
    rd.x = 1.0f/(a0 + ws.x); rd.y = 1.0f/(a1 + ws.y);
    rd.z = 1.0f/(a2 + ws.z); rd.w = 1.0f/(a3 + ws.w);
    *(float4*)&rdenN[node*4] = rd;
    *(float4*)&wvS[node*4] = ws;
  }
}

__global__ void k_edgew2(const float* __restrict__ asrc, const float* __restrict__ adst,
                         const int* __restrict__ offs, const int* __restrict__ cnt,
                         const int* __restrict__ csr,
                         float* __restrict__ wvE, float* __restrict__ rdenN,
                         float* __restrict__ wvS, int N){
  int node = blockIdx.x*4 + (threadIdx.x >> 6);
  int lane = threadIdx.x & 63;
  if(node >= N) return;
  float ad = adst[node];
  float acc = 0.f;
  int e0 = offs[node], e1 = e0 + cnt[node];
  for(int e = e0 + lane; e < e1; e += 64){
    float w = expf(lrelu(asrc[csr[e]] + ad));
    acc += w;
    wvE[e] = w;
  }
  #pragma unroll
  for(int d = 32; d >= 1; d >>= 1) acc += __shfl_xor(acc, d, 64);
  float ws = expf(lrelu(asrc[node] + ad));
  if(lane == 0){
    rdenN[node] = 1.0f/(acc + ws);
    wvS[node] = ws;
  }
}

// ---------------- layer-1 one-pass pre-aggregation over xb ----------------
__global__ void k_aggx(const unsigned short* __restrict__ xb,
                       const float* __restrict__ wvE, const float* __restrict__ rden,
                       const float* __restrict__ wvS,
                       const float* __restrict__ dis, const float* __restrict__ invc,
                       const int* __restrict__ offs, const int* __restrict__ cnt,
                       const int* __restrict__ csr,
                       unsigned short* __restrict__ z, unsigned short* __restrict__ agcnx,
                       unsigned short* __restrict__ asagex, int N){
  int node = blockIdx.x*4 + (threadIdx.x >> 6);
  int lane = threadIdx.x & 63;
  if(node >= N) return;
  int half = lane >> 5, subl = lane & 31;      // subl*2, subl*2+1 channels
  float zg[4][2] = {{0,0},{0,0},{0,0},{0,0}};
  float gg[2] = {0,0}, ssv[2] = {0,0};
  int e0 = offs[node], e1 = e0 + cnt[node];
  #pragma unroll 2
  for(int e = e0 + half; e < e1; e += 2){
    int s = csr[e];
    float4 w4 = *(const float4*)&wvE[(size_t)e*4];
    float ds = dis[s];
    unsigned int u = *(const unsigned int*)&xb[(size_t)s*64 + subl*2];
    float xl = bflo(u), xh = bfhi(u);
    zg[0][0] = fmaf(w4.x, xl, zg[0][0]); zg[0][1] = fmaf(w4.x, xh, zg[0][1]);
    zg[1][0] = fmaf(w4.y, xl, zg[1][0]); zg[1][1] = fmaf(w4.y, xh, zg[1][1]);
    zg[2][0] = fmaf(w4.z, xl, zg[2][0]); zg[2][1] = fmaf(w4.z, xh, zg[2][1]);
    zg[3][0] = fmaf(w4.w, xl, zg[3][0]); zg[3][1] = fmaf(w4.w, xh, zg[3][1]);
    gg[0] = fmaf(ds, xl, gg[0]); gg[1] = fmaf(ds, xh, gg[1]);
    ssv[0] += xl; ssv[1] += xh;
  }
  #pragma unroll
  for(int h = 0; h < 4; h++){
    zg[h][0] += __shfl_xor(zg[h][0], 32, 64);
    zg[h][1] += __shfl_xor(zg[h][1], 32, 64);
  }
  gg[0] += __shfl_xor(gg[0], 32, 64); gg[1] += __shfl_xor(gg[1], 32, 64);
  ssv[0] += __shfl_xor(ssv[0], 32, 64); ssv[1] += __shfl_xor(ssv[1], 32, 64);
  if(half == 0){
    unsigned int un = *(const unsigned int*)&xb[(size_t)node*64 + subl*2];
    float xl = bflo(un), xh = bfhi(un);
    float4 ws4 = *(const float4*)&wvS[node*4];
    float4 rd4 = *(const float4*)&rden[node*4];
    unsigned int* zp = (unsigned int*)&z[(size_t)node*256 + subl*2];
    zp[0]   = pack2((zg[0][0] + ws4.x*xl)*rd4.x, (zg[0][1] + ws4.x*xh)*rd4.x);
    zp[32]  = pack2((zg[1][0] + ws4.y*xl)*rd4.y, (zg[1][1] + ws4.y*xh)*rd4.y);
    zp[64]  = pack2((zg[2][0] + ws4.z*xl)*rd4.z, (zg[2][1] + ws4.z*xh)*rd4.z);
    zp[96]  = pack2((zg[3][0] + ws4.w*xl)*rd4.w, (zg[3][1] + ws4.w*xh)*rd4.w);
    float dc = dis[node], ic = invc[node];
    *(unsigned int*)&agcnx[(size_t)node*64 + subl*2] =
        pack2(dc*fmaf(dc, xl, gg[0]), dc*fmaf(dc, xh, gg[1]));
    *(unsigned int*)&asagex[(size_t)node*64 + subl*2] = pack2(ssv[0]*ic, ssv[1]*ic);
  }
}

// ---------------- layer-2 one-pass pre-aggregation over a1 / s1 / h2 ----------------
__global__ void k_aggf(const unsigned short* __restrict__ a1, const unsigned short* __restrict__ s1,
                       const unsigned short* __restrict__ h2,
                       const float* __restrict__ wvE, const float* __restrict__ rden,
                       const float* __restrict__ wvS,
                       const float* __restrict__ dis, const float* __restrict__ invc,
                       const int* __restrict__ offs, const int* __restrict__ cnt,
                       const int* __restrict__ csr,
                       unsigned short* __restrict__ A2agg, unsigned short* __restrict__ S2agg,
                       unsigned short* __restrict__ T2, int N){
  int node = blockIdx.x*4 + (threadIdx.x >> 6);
  int lane = threadIdx.x & 63;
  if(node >= N) return;
  int half = lane >> 5, subl = lane & 31;
  float aa[2] = {0,0}, ss[2] = {0,0}, tt[2] = {0,0};
  int e0 = offs[node], e1 = e0 + cnt[node];
  #pragma unroll 2
  for(int e = e0 + half; e < e1; e += 2){
    int s = csr[e];
    float ds = dis[s];
    float wv = wvE[e];
    unsigned int ua = *(const unsigned int*)&a1[(size_t)s*64 + subl*2];
    unsigned int us = *(const unsigned int*)&s1[(size_t)s*64 + subl*2];
    unsigned int uh = *(const unsigned int*)&h2[(size_t)s*64 + subl*2];
    aa[0] = fmaf(ds, bflo(ua), aa[0]); aa[1] = fmaf(ds, bfhi(ua), aa[1]);
    ss[0] += bflo(us); ss[1] += bfhi(us);
    tt[0] = fmaf(wv, bflo(uh), tt[0]); tt[1] = fmaf(wv, bfhi(uh), tt[1]);
  }
  aa[0] += __shfl_xor(aa[0], 32, 64); aa[1] += __shfl_xor(aa[1], 32, 64);
  ss[0] += __shfl_xor(ss[0], 32, 64); ss[1] += __shfl_xor(ss[1], 32, 64);
  tt[0] += __shfl_xor(tt[0], 32, 64); tt[1] += __shfl_xor(tt[1], 32, 64);
  if(half == 0){
    unsigned int uan = *(const unsigned int*)&a1[(size_t)node*64 + subl*2];
    unsigned int uhn = *(const unsigned int*)&h2[(size_t)node*64 + subl*2];
    float dc = dis[node], ic = invc[node];
    float rd = rden[node], wss = wvS[node];
    *(unsigned int*)&A2agg[(size_t)node*64 + subl*2] =
        pack2(dc*fmaf(dc, bflo(uan), aa[0]), dc*fmaf(dc, bfhi(uan), aa[1]));
    *(unsigned int*)&S2agg[(size_t)node*64 + subl*2] = pack2(ss[0]*ic, ss[1]*ic);
    *(unsigned int*)&T2[(size_t)node*64 + subl*2] =
        pack2(fmaf(wss, bflo(uhn), tt[0])*rd, fmaf(wss, bfhi(uhn), tt[1])*rd);
  }
}

// ---------------- MFMA bf16 matmul, LDS-free (B from packed WT[col][k]) ----------------
// ep: 0 = plain; 1 = BN+relu; 2 = ELU; 3 = sage(+bias, row L2-norm, relu); 4 = plain + att dots
// NOTE: col0 is the single source of column offset — it indexes WT, C, and bias.
struct MME {
  const unsigned short* A; const unsigned short* WT;    // WT row stride = K
  const unsigned short* A2; const unsigned short* WT2;  // optional 2nd segment, K2=64
  unsigned short* C;
  const float* b; const float* p1; const float* p2;
  float* y1; float* y2;
  int lda, ldc, col0, K, ep;
};
struct MMP { MME e[6]; int N; };

__global__ __launch_bounds__(256) void k_mm_mfma(MMP p){
  MME m = p.e[blockIdx.y];
  const int N = p.N, K = m.K;
  int tid = threadIdx.x;
  int w = tid >> 6, lane = tid & 63, quad = lane >> 4, m16 = lane & 15;
  int rowa = blockIdx.x*64 + w*16 + m16;
  int rowc = rowa < N ? rowa : N - 1;
  f32x4 acc[4];
  #pragma unroll
  for(int t = 0; t < 4; t++){ acc[t][0]=0.f; acc[t][1]=0.f; acc[t][2]=0.f; acc[t][3]=0.f; }
  for(int kc = 0; kc < K; kc += 64){
    bf16x8 a0 = *(const bf16x8*)&m.A[(size_t)rowc*m.lda + kc + quad*8];
    bf16x8 a1 = *(const bf16x8*)&m.A[(size_t)rowc*m.lda + kc + 32 + quad*8];
    #pragma unroll
    for(int t = 0; t < 4; t++){
      const unsigned short* wr = &m.WT[(size_t)(m.col0 + t*16 + m16)*K + kc + quad*8];
      bf16x8 b0 = *(const bf16x8*)wr;
      bf16x8 b1 = *(const bf16x8*)(wr + 32);
      acc[t] = __builtin_amdgcn_mfma_f32_16x16x32_bf16(a0, b0, acc[t], 0, 0, 0);
      acc[t] = __builtin_amdgcn_mfma_f32_16x16x32_bf16(a1, b1, acc[t], 0, 0, 0);
    }
  }
  if(m.A2){
    bf16x8 a0 = *(const bf16x8*)&m.A2[(size_t)rowc*64 + quad*8];
    bf16x8 a1 = *(const bf16x8*)&m.A2[(size_t)rowc*64 + 32 + quad*8];
    #pragma unroll
    for(int t = 0; t < 4; t++){
      const unsigned short* wr = &m.WT2[(size_t)(t*16 + m16)*64 + quad*8];
      bf16x8 b0 = *(const bf16x8*)wr;
      bf16x8 b1 = *(const bf16x8*)(wr + 32);
      acc[t] = __builtin_amdgcn_mfma_f32_16x16x32_bf16(a0, b0, acc[t], 0, 0, 0);
      acc[t] = __builtin_amdgcn_mfma_f32_16x16x32_bf16(a1, b1, acc[t], 0, 0, 0);
    }
  }
  int robase = blockIdx.x*64 + w*16 + quad*4;
  if(m.ep == 3){
    float v[4][4], n2[4] = {0,0,0,0};
    #pragma unroll
    for(int t = 0; t < 4; t++){
      float bv = m.b[m.col0 + t*16 + m16];
      #pragma unroll
      for(int r = 0; r < 4; r++){ v[t][r] = acc[t][r] + bv; n2[r] = fmaf(v[t][r], v[t][r], n2[r]); }
    }
    #pragma unroll
    for(int d = 8; d >= 1; d >>= 1){
      #pragma unroll
      for(int r = 0; r < 4; r++) n2[r] += __shfl_xor(n2[r], d, 64);
    }
    float inv[4];
    #pragma unroll
    for(int r = 0; r < 4; r++) inv[r] = 1.0f / fmaxf(sqrtf(n2[r]), 1e-12f);
    #pragma unroll
    for(int t = 0; t < 4; t++){
      #pragma unroll
      for(int r = 0; r < 4; r++){
        int ro = robase + r;
        if(ro < N) m.C[(size_t)ro*m.ldc + m.col0 + t*16 + m16] = f2bf(fmaxf(v[t][r]*inv[r], 0.f));
      }
    }
    return;
  }
  #pragma unroll
  for(int t = 0; t < 4; t++){
    int col = m.col0 + t*16 + m16;
    float bv = (m.ep == 1 || m.ep == 2) ? m.b[col] : 0.f;
    float gm = (m.ep == 1) ? m.p1[col]*rsqrtf(1.0f + 1e-5f) : 0.f;
    float be = (m.ep == 1) ? m.p2[col] : 0.f;
    #pragma unroll
    for(int r = 0; r < 4; r++){
      int ro = robase + r;
      if(ro < N){
        float val = acc[t][r];
        if(m.ep == 1)      val = fmaxf((val + bv)*gm + be, 0.f);
        else if(m.ep == 2) val = elu1(val + bv);
        m.C[(size_t)ro*m.ldc + col] = f2bf(val);
      }
    }
  }
  if(m.ep == 4){
    float ps[4] = {0,0,0,0}, pd[4] = {0,0,0,0};
    #pragma unroll
    for(int t = 0; t < 4; t++){
      int col = m.col0 + t*16 + m16;
      float a_ = m.p1[col], d_ = m.p2[col];
      #pragma unroll
      for(int r = 0; r < 4; r++){ ps[r] = fmaf(acc[t][r], a_, ps[r]); pd[r] = fmaf(acc[t][r], d_, pd[r]); }
    }
    #pragma unroll
    for(int d = 8; d >= 1; d >>= 1){
      #pragma unroll
      for(int r = 0; r < 4; r++){ ps[r] += __shfl_xor(ps[r], d, 64); pd[r] += __shfl_xor(pd[r], d, 64); }
    }
    if(m16 == 0){
      #pragma unroll
      for(int r = 0; r < 4; r++){
        int ro = robase + r;
        if(ro < N){ m.y1[ro] = ps[r]; m.y2[ro] = pd[r]; }
      }
    }
  }
}

// ---------------- final: GCN2 mm + SAGE2 dual mm + L2norm + GAT2 add + gate combine ----------------
__global__ __launch_bounds__(256) void k_mm_final(
    const unsigned short* __restrict__ A2agg, const unsigned short* __restrict__ WTg,
    const float* __restrict__ gcn_b2,
    const unsigned short* __restrict__ S2agg, const unsigned short* __restrict__ WTl,
    const float* __restrict__ bl2,
    const unsigned short* __restrict__ s1, const unsigned short* __restrict__ WTr,
    const unsigned short* __restrict__ T2, const float* __restrict__ gat_b2,
    const float* __restrict__ gatew, float* __restrict__ out, int N){
  int tid = threadIdx.x;
  int w = tid >> 6, lane = tid & 63, quad = lane >> 4, m16 = lane & 15;
  int rowa = blockIdx.x*64 + w*16 + m16;
  int rowc = rowa < N ? rowa : N - 1;
  f32x4 accg[4], accs[4];
  #pragma unroll
  for(int t = 0; t < 4; t++){
    accg[t][0]=0.f; accg[t][1]=0.f; accg[t][2]=0.f; accg[t][3]=0.f;
    accs[t][0]=0.f; accs[t][1]=0.f; accs[t][2]=0.f; accs[t][3]=0.f;
  }
  {
    bf16x8 a0 = *(const bf16x8*)&A2agg[(size_t)rowc*64 + quad*8];
    bf16x8 a1 = *(const bf16x8*)&A2agg[(size_t)rowc*64 + 32 + quad*8];
    bf16x8 c0 = *(const bf16x8*)&S2agg[(size_t)rowc*64 + quad*8];
    bf16x8 c1 = *(const bf16x8*)&S2agg[(size_t)rowc*64 + 32 + quad*8];
    bf16x8 d0 = *(const bf16x8*)&s1[(size_t)rowc*64 + quad*8];
    bf16x8 d1 = *(const bf16x8*)&s1[(size_t)rowc*64 + 32 + quad*8];
    #pragma unroll
    for(int t = 0; t < 4; t++){
      const unsigned short* wg = &WTg[(size_t)(t*16 + m16)*64 + quad*8];
      const unsigned short* wl = &WTl[(size_t)(t*16 + m16)*64 + quad*8];
      const unsigned short* wr = &WTr[(size_t)(t*16 + m16)*64 + quad*8];
      accg[t] = __builtin_amdgcn_mfma_f32_16x16x32_bf16(a0, *(const bf16x8*)wg, accg[t], 0, 0, 0);
      accg[t] = __builtin_amdgcn_mfma_f32_16x16x32_bf16(a1, *(const bf16x8*)(wg+32), accg[t], 0, 0, 0);
      accs[t] = __builtin_amdgcn_mfma_f32_16x16x32_bf16(c0, *(const bf16x8*)wl, accs[t], 0, 0, 0);
      accs[t] = __builtin_amdgcn_mfma_f32_16x16x32_bf16(c1, *(const bf16x8*)(wl+32), accs[t], 0, 0, 0);
      accs[t] = __builtin_amdgcn_mfma_f32_16x16x32_bf16(d0, *(const bf16x8*)wr, accs[t], 0, 0, 0);
      accs[t] = __builtin_amdgcn_mfma_f32_16x16x32_bf16(d1, *(const bf16x8*)(wr+32), accs[t], 0, 0, 0);
    }
  }
  float w0 = gatew[0], w1 = gatew[1], w2 = gatew[2];
  int robase = blockIdx.x*64 + w*16 + quad*4;
  float vs[4][4], n2[4] = {0,0,0,0};
  #pragma unroll
  for(int t = 0; t < 4; t++){
    float bsv = bl2[t*16 + m16];
    #pragma unroll
    for(int r = 0; r < 4; r++){ vs[t][r] = accs[t][r] + bsv; n2[r] = fmaf(vs[t][r], vs[t][r], n2[r]); }
  }
  #pragma unroll
  for(int d = 8; d >= 1; d >>= 1){
    #pragma unroll
    for(int r = 0; r < 4; r++) n2[r] += __shfl_xor(n2[r], d, 64);
  }
  float inv[4];
  #pragma unroll
  for(int r = 0; r < 4; r++) inv[r] = 1.0f / fmaxf(sqrtf(n2[r]), 1e-12f);
  #pragma unroll
  for(int t = 0; t < 4; t++){
    int col = t*16 + m16;
    float bg = gcn_b2[col], bt = gat_b2[col];
    #pragma unroll
    for(int r = 0; r < 4; r++){
      int ro = robase + r;
      if(ro < N){
        float t2 = bflo((unsigned int)T2[(size_t)ro*64 + col]);
        out[(size_t)ro*64 + col] = w0*(accg[t][r] + bg) + w1*(t2 + bt) + w2*vs[t][r]*inv[r];
      }
    }
  }
}

// ---------------- host ----------------
extern "C" void kernel_launch(void* const* d_in, const int* in_sizes, int n_in,
                              void* d_out, int out_size, void* d_ws, size_t ws_size,
                              hipStream_t stream){
  const float* x        = (const float*)d_in[0];
  const int*   ei       = (const int*)d_in[1];
  const int*   row      = ei;
  const int*   col      = ei + NE;
  const float* gate_w1  = (const float*)d_in[2];
  const float* gate_b1  = (const float*)d_in[3];
  const float* gate_w2  = (const float*)d_in[4];
  const float* gate_b2  = (const float*)d_in[5];
  const float* gcn_w1   = (const float*)d_in[6];
  const float* gcn_b1   = (const float*)d_in[7];
  const float* bn_gamma = (const float*)d_in[8];
  const float* bn_beta  = (const float*)d_in[9];
  const float* gcn_w2   = (const float*)d_in[10];
  const float* gcn_b2   = (const float*)d_in[11];
  const float* gat_w1   = (const float*)d_in[12];
  const float* gat_as1  = (const float*)d_in[13];
  const float* gat_ad1  = (const float*)d_in[14];
  const float* gat_b1   = (const float*)d_in[15];
  const float* gat_w2   = (const float*)d_in[16];
  const float* gat_as2  = (const float*)d_in[17];
  const float* gat_ad2  = (const float*)d_in[18];
  const float* gat_b2   = (const float*)d_in[19];
  const float* sage_wl1 = (const float*)d_in[20];
  const float* sage_bl1 = (const float*)d_in[21];
  const float* sage_wr1 = (const float*)d_in[22];
  const float* sage_wl2 = (const float*)d_in[23];
  const float* sage_bl2 = (const float*)d_in[24];
  const float* sage_wr2 = (const float*)d_in[25];
  float* out = (float*)d_out;

  char* wp = (char*)d_ws;
  auto alloc = [&](size_t bytes)->char*{ char* p = wp; wp += (bytes + 255) & ~(size_t)255; return p; };
  // zero-init region (contiguous): cnt, cursor, gsum, total
  int*   cnt    = (int*)  alloc((size_t)NN*4);
  int*   cursor = (int*)  alloc((size_t)NN*4);
  float* gsum   = (float*)alloc(64*4);
  int*   total  = (int*)  alloc(256);
  size_t zbytes = (size_t)(wp - (char*)cnt);
  int*   offs   = (int*)  alloc((size_t)NN*4);
  int*   csr    = (int*)  alloc((size_t)NE*4);
  float* dis    = (float*)alloc((size_t)NN*4);
  float* invc   = (float*)alloc((size_t)NN*4);
  float* gatew  = (float*)alloc(16);
  float* wsd    = (float*)alloc(64*8*4);
  float* asrc1  = (float*)alloc((size_t)NN*4*4);
  float* adst1  = (float*)alloc((size_t)NN*4*4);
  float* asrc2  = (float*)alloc((size_t)NN*4);
  float* adst2  = (float*)alloc((size_t)NN*4);
  float* wvE1   = (float*)alloc((size_t)NE*4*4);
  float* rden1  = (float*)alloc((size_t)NN*4*4);
  float* wvS1   = (float*)alloc((size_t)NN*4*4);
  float* wvE2   = (float*)alloc((size_t)NE*4);
  float* rden2  = (float*)alloc((size_t)NN*4);
  float* wvS2   = (float*)alloc((size_t)NN*4);
  // packed bf16 transposed weights
  unsigned short* WT_gcn1 = (unsigned short*)alloc(64*64*2);
  unsigned short* WT_sl1  = (unsigned short*)alloc(64*64*2);
  unsigned short* WT_sr1  = (unsigned short*)alloc(64*64*2);
  unsigned short* WT_gat1 = (unsigned short*)alloc(256*64*2);
  unsigned short* WT_gat2 = (unsigned short*)alloc(64*256*2);
  unsigned short* WT_gcn2 = (unsigned short*)alloc(64*64*2);
  unsigned short* WT_sl2  = (unsigned short*)alloc(64*64*2);
  unsigned short* WT_sr2  = (unsigned short*)alloc(64*64*2);
  unsigned short* xb     = (unsigned short*)alloc((size_t)NN*64*2);
  unsigned short* z      = (unsigned short*)alloc((size_t)NN*256*2);
  unsigned short* agcnx  = (unsigned short*)alloc((size_t)NN*64*2);
  unsigned short* asagex = (unsigned short*)alloc((size_t)NN*64*2);
  unsigned short* a1     = (unsigned short*)alloc((size_t)NN*64*2);
  unsigned short* s1     = (unsigned short*)alloc((size_t)NN*64*2);
  unsigned short* gath   = (unsigned short*)alloc((size_t)NN*256*2);
  unsigned short* h2     = (unsigned short*)alloc((size_t)NN*64*2);
  unsigned short* A2agg  = (unsigned short*)alloc((size_t)NN*64*2);
  unsigned short* S2agg  = (unsigned short*)alloc((size_t)NN*64*2);
  unsigned short* T2     = (unsigned short*)alloc((size_t)NN*64*2);

  hipMemsetAsync(cnt, 0, zbytes, stream);

  const int gN  = (NN + 63) / 64;   // 782
  const int g4  = NN / 4;           // 12500
  const int g16 = NN / 16;          // 3125
  const int gA  = (NN + 255) / 256; // 196

  // pack weights (tiny)
  {
    PKP p = {};
    p.e[0] = {gcn_w1,   WT_gcn1, 64,  64};
    p.e[1] = {sage_wl1, WT_sl1,  64,  64};
    p.e[2] = {sage_wr1, WT_sr1,  64,  64};
    p.e[3] = {gat_w1,   WT_gat1, 256, 64};
    p.e[4] = {gat_w2,   WT_gat2, 64,  256};
    p.e[5] = {gcn_w2,   WT_gcn2, 64,  64};
    p.e[6] = {sage_wl2, WT_sl2,  64,  64};
    p.e[7] = {sage_wr2, WT_sr2,  64,  64};
    k_pack<<<8, 256, 0, stream>>>(p);
  }

  k_count<<<(NE+255)/256, 256, 0, stream>>>(col, cnt, NE);
  k_alloc<<<gA, 256, 0, stream>>>(cnt, offs, dis, invc, total, NN);
  k_fill <<<(NE+255)/256, 256, 0, stream>>>(row, col, offs, cursor, csr, NE);
  k_castsum<<<256, 256, 0, stream>>>(x, xb, gsum, NN);
  k_gate  <<<1, 64, 0, stream>>>(gsum, gate_w1, gate_b1, gate_w2, gate_b2, gatew);
  k_fold1 <<<1, 256, 0, stream>>>(gat_w1, gat_as1, gat_ad1, wsd);
  k_attdotx<<<g16, 256, 0, stream>>>(xb, wsd, asrc1, adst1, NN);
  k_edgew1<<<g4, 256, 0, stream>>>(asrc1, adst1, offs, cnt, csr, wvE1, rden1, wvS1, NN);

  // ---- layer-1 one-pass pre-aggregation over xb ----
  k_aggx<<<g4, 256, 0, stream>>>(xb, wvE1, rden1, wvS1, dis, invc, offs, cnt, csr,
                                 z, agcnx, asagex, NN);

  // ---- layer-1 matmuls with fused activations (6 entries, one dispatch, LDS-free) ----
  {
    MMP p = {};
    p.N = NN;
    p.e[0] = {agcnx, WT_gcn1, nullptr, nullptr, a1, gcn_b1, bn_gamma, bn_beta,
              nullptr, nullptr, 64, 64, 0, 64, 1};
    p.e[1] = {asagex, WT_sl1, xb, WT_sr1, s1, sage_bl1, nullptr, nullptr,
              nullptr, nullptr, 64, 64, 0, 64, 3};
    // NOTE: WT_gat1 is NOT pre-offset — col0 indexes both WT rows and C columns.
    for(int hd = 0; hd < 4; hd++)
      p.e[2+hd] = {z + hd*64, WT_gat1, nullptr, nullptr, gath, gat_b1,
                   nullptr, nullptr, nullptr, nullptr, 256, 256, hd*64, 64, 2};
    k_mm_mfma<<<dim3(gN,6), 256, 0, stream>>>(p);
  }

  // ---- GAT layer 2 matmul (K=256) + folded attention dots ----
  {
    MMP p = {};
    p.N = NN;
    p.e[0] = {gath, WT_gat2, nullptr, nullptr, h2, nullptr, gat_as2, gat_ad2,
              asrc2, adst2, 256, 64, 0, 256, 4};
    k_mm_mfma<<<dim3(gN,1), 256, 0, stream>>>(p);
  }
  k_edgew2<<<g4, 256, 0, stream>>>(asrc2, adst2, offs, cnt, csr, wvE2, rden2, wvS2, NN);

  // ---- layer-2 one-pass pre-aggregation ----
  k_aggf<<<g4, 256, 0, stream>>>(a1, s1, h2, wvE2, rden2, wvS2, dis, invc,
                                 offs, cnt, csr, A2agg, S2agg, T2, NN);

  // ---- final matmuls + gate combine (LDS-free) ----
  k_mm_final<<<gN, 256, 0, stream>>>(A2agg, WT_gcn2, gcn_b2, S2agg, WT_sl2, sage_bl2,
                                     s1, WT_sr2, T2, gat_b2, gatew, out, NN);
}

// Round 10
// 392.755 us; speedup vs baseline: 1.0173x; 1.0173x over previous
//
#include <hip/hip_runtime.h>
#include <hip/hip_bf16.h>
#include <math.h>

#define NN 50000
#define NE 400000

typedef __attribute__((ext_vector_type(8))) short bf16x8;
typedef __attribute__((ext_vector_type(4))) float f32x4;

// ---------------- helpers ----------------
__device__ __forceinline__ float lrelu(float v){ return v > 0.f ? v : 0.2f*v; }
__device__ __forceinline__ float elu1(float v){ return v > 0.f ? v : expm1f(v); }
__device__ __forceinline__ float bflo(unsigned int u){ return __uint_as_float(u << 16); }
__device__ __forceinline__ float bfhi(unsigned int u){ return __uint_as_float(u & 0xffff0000u); }
__device__ __forceinline__ unsigned short f2bf(float f){
  __hip_bfloat16 h = __float2bfloat16(f);
  return *(unsigned short*)&h;
}
__device__ __forceinline__ unsigned int pack2(float lo, float hi){
  return (unsigned int)f2bf(lo) | ((unsigned int)f2bf(hi) << 16);
}

// ---------------- CSR build ----------------
__global__ void k_count(const int* __restrict__ col, int* __restrict__ cnt, int E){
  int e = blockIdx.x*blockDim.x + threadIdx.x;
  if(e < E) atomicAdd(&cnt[col[e]], 1);
}

__global__ void k_alloc(const int* __restrict__ cnt, int* __restrict__ offs,
                        float* __restrict__ dis, float* __restrict__ invc,
                        int* __restrict__ total, int N){
  int i = blockIdx.x*blockDim.x + threadIdx.x;
  int lane = threadIdx.x & 63;
  int v = (i < N) ? cnt[i] : 0;
  int x = v;
  #pragma unroll
  for(int d = 1; d < 64; d <<= 1){ int t = __shfl_up(x, d, 64); if(lane >= d) x += t; }
  int base = 0;
  if(lane == 63 && x > 0) base = atomicAdd(total, x);
  base = __shfl(base, 63, 64);
  if(i < N){
    offs[i] = base + x - v;
    dis[i]  = 1.0f / sqrtf((float)(v + 1));
    invc[i] = 1.0f / fmaxf((float)v, 1.0f);
  }
}

__global__ void k_fill(const int* __restrict__ row, const int* __restrict__ col,
                       const int* __restrict__ offs, int* __restrict__ cursor,
                       int* __restrict__ csr, int E){
  int e = blockIdx.x*blockDim.x + threadIdx.x;
  if(e < E){
    int c = col[e];
    int pos = offs[c] + atomicAdd(&cursor[c], 1);
    csr[pos] = row[e];
  }
}

// ---------------- pack weights -> bf16 transposed WT[col][k] ----------------
struct PKE { const float* W; unsigned short* T; int C, K; };
struct PKP { PKE e[8]; };
__global__ void k_pack(PKP p){
  PKE m = p.e[blockIdx.x];
  int total = m.C * m.K;
  for(int i = threadIdx.x; i < total; i += 256){
    int c = i / m.K, k = i - c*m.K;
    m.T[i] = f2bf(m.W[(size_t)k*m.C + c]);
  }
}

// ---------------- cast x -> bf16 + column sums for gate ----------------
__global__ void k_castsum(const float* __restrict__ x, unsigned short* __restrict__ xb,
                          float* __restrict__ gsum, int N){
  __shared__ float part[4][64];
  int lane = threadIdx.x & 63, w = threadIdx.x >> 6;
  float s = 0.f;
  for(int r = blockIdx.x*4 + w; r < N; r += gridDim.x*4){
    float v = x[(size_t)r*64 + lane];
    xb[(size_t)r*64 + lane] = f2bf(v);
    s += v;
  }
  part[w][lane] = s;
  __syncthreads();
  if(w == 0) atomicAdd(&gsum[lane], part[0][lane]+part[1][lane]+part[2][lane]+part[3][lane]);
}

__global__ void k_gate(const float* __restrict__ gsum,
                       const float* __restrict__ w1, const float* __restrict__ b1,
                       const float* __restrict__ w2, const float* __restrict__ b2,
                       float* __restrict__ gatew){
  __shared__ float g[64]; __shared__ float hid[64]; __shared__ float lg[3];
  int t = threadIdx.x;
  g[t] = gsum[t] * (1.0f/(float)NN);
  __syncthreads();
  float acc = b1[t];
  for(int i = 0; i < 64; i++) acc += g[i]*w1[i*64 + t];
  hid[t] = fmaxf(acc, 0.f);
  __syncthreads();
  if(t < 3){
    float a = b2[t];
    for(int j = 0; j < 64; j++) a += hid[j]*w2[j*3 + t];
    lg[t] = a;
  }
  __syncthreads();
  if(t == 0){
    float m = fmaxf(lg[0], fmaxf(lg[1], lg[2]));
    float e0 = expf(lg[0]-m), e1 = expf(lg[1]-m), e2 = expf(lg[2]-m);
    float s = e0 + e1 + e2;
    gatew[0] = e0/s; gatew[1] = e1/s; gatew[2] = e2/s;
  }
}

// ---------------- fold GAT1 attention vectors through W ----------------
__global__ void k_fold1(const float* __restrict__ w1, const float* __restrict__ as,
                        const float* __restrict__ ad, float* __restrict__ wsd){
  int t = threadIdx.x;            // 256
  int k = t & 63, h = t >> 6;
  float ssrc = 0.f, sdst = 0.f;
  for(int c = 0; c < 64; c++){
    float w = w1[k*256 + h*64 + c];
    ssrc += w * as[h*64 + c];
    sdst += w * ad[h*64 + c];
  }
  wsd[k*8 + h] = ssrc;
  wsd[k*8 + 4 + h] = sdst;
}

// ---------------- asrc1/adst1 = xb @ Wsd  (16 lanes per node) ----------------
__global__ void k_attdotx(const unsigned short* __restrict__ xb, const float* __restrict__ wsd,
                          float* __restrict__ asrc, float* __restrict__ adst, int N){
  __shared__ float ws[64*8];
  int tid = threadIdx.x;
  ws[tid] = wsd[tid];
  ws[tid + 256] = wsd[tid + 256];
  __syncthreads();
  int node = blockIdx.x*16 + (tid >> 4);
  int l = tid & 15;
  if(node >= N) return;
  uint2 u = *(const uint2*)&xb[(size_t)node*64 + l*4];
  float v0 = bflo(u.x), v1 = bfhi(u.x), v2 = bflo(u.y), v3 = bfhi(u.y);
  float s[8];
  #pragma unroll
  for(int h = 0; h < 8; h++){
    s[h] = v0*ws[(l*4+0)*8+h] + v1*ws[(l*4+1)*8+h] + v2*ws[(l*4+2)*8+h] + v3*ws[(l*4+3)*8+h];
  }
  #pragma unroll
  for(int d = 8; d >= 1; d >>= 1){
    #pragma unroll
    for(int h = 0; h < 8; h++) s[h] += __shfl_xor(s[h], d, 16);
  }
  if(l == 0){
    float4 o1; o1.x = s[0]; o1.y = s[1]; o1.z = s[2]; o1.w = s[3];
    float4 o2; o2.x = s[4]; o2.y = s[5]; o2.z = s[6]; o2.w = s[7];
    *(float4*)&asrc[node*4] = o1;
    *(float4*)&adst[node*4] = o2;
  }
}

// ---------------- GAT edge weights ----------------
__global__ void k_edgew1(const float* __restrict__ asrc, const float* __restrict__ adst,
                         const int* __restrict__ offs, const int* __restrict__ cnt,
                         const int* __restrict__ csr,
                         float* __restrict__ wvE, float* __restrict__ rdenN,
                         float* __restrict__ wvS, int N){
  int node = blockIdx.x*4 + (threadIdx.x >> 6);
  int lane = threadIdx.x & 63;
  if(node >= N) return;
  float4 ad = *(const float4*)&adst[node*4];
  float a0 = 0.f, a1 = 0.f, a2 = 0.f, a3 = 0.f;
  int e0 = offs[node], e1 = e0 + cnt[node];
  for(int e = e0 + lane; e < e1; e += 64){
    int s = csr[e];
    float4 as = *(const float4*)&asrc[s*4];
    float4 w;
    w.x = expf(lrelu(as.x + ad.x));
    w.y = expf(lrelu(as.y + ad.y));
    w.z = expf(lrelu(as.z + ad.z));
    w.w = expf(lrelu(as.w + ad.w));
    a0 += w.x; a1 += w.y; a2 += w.z; a3 += w.w;
    *(float4*)&wvE[(size_t)e*4] = w;
  }
  #pragma unroll
  for(int d = 32; d >= 1; d >>= 1){
    a0 += __shfl_xor(a0, d, 64); a1 += __shfl_xor(a1, d, 64);
    a2 += __shfl_xor(a2, d, 64); a3 += __shfl_xor(a3, d, 64);
  }
  float4 asl = *(const float4*)&asrc[node*4];
  float4 ws;
  ws.x = expf(lrelu(asl.x + ad.x));
  ws.y = expf(lrelu(asl.y + ad.y));
  ws.z = expf(lrelu(asl.z + ad.z));
  ws.w = expf(lrelu(asl.w + ad.w));
  if(lane == 0){
    float4 rd;
    rd.x = 1.0f/(a0 + ws.x); rd.y = 1.0f/(a1 + ws.y);
    rd.z = 1.0f/(a2 + ws.z); rd.w = 1.0f/(a3 + ws.w);
    *(float4*)&rdenN[node*4] = rd;
    *(float4*)&wvS[node*4] = ws;
  }
}

__global__ void k_edgew2(const float* __restrict__ asrc, const float* __restrict__ adst,
                         const int* __restrict__ offs, const int* __restrict__ cnt,
                         const int* __restrict__ csr,
                         float* __restrict__ wvE, float* __restrict__ rdenN,
                         float* __restrict__ wvS, int N){
  int node = blockIdx.x*4 + (threadIdx.x >> 6);
  int lane = threadIdx.x & 63;
  if(node >= N) return;
  float ad = adst[node];
  float acc = 0.f;
  int e0 = offs[node], e1 = e0 + cnt[node];
  for(int e = e0 + lane; e < e1; e += 64){
    float w = expf(lrelu(asrc[csr[e]] + ad));
    acc += w;
    wvE[e] = w;
  }
  #pragma unroll
  for(int d = 32; d >= 1; d >>= 1) acc += __shfl_xor(acc, d, 64);
  float ws = expf(lrelu(asrc[node] + ad));
  if(lane == 0){
    rdenN[node] = 1.0f/(acc + ws);
    wvS[node] = ws;
  }
}

// ---------------- layer-1 one-pass pre-aggregation over xb ----------------
__global__ void k_aggx(const unsigned short* __restrict__ xb,
                       const float* __restrict__ wvE, const float* __restrict__ rden,
                       const float* __restrict__ wvS,
                       const float* __restrict__ dis, const float* __restrict__ invc,
                       const int* __restrict__ offs, const int* __restrict__ cnt,
                       const int* __restrict__ csr,
                       unsigned short* __restrict__ z, unsigned short* __restrict__ agcnx,
                       unsigned short* __restrict__ asagex, int N){
  int node = blockIdx.x*4 + (threadIdx.x >> 6);
  int lane = threadIdx.x & 63;
  if(node >= N) return;
  int half = lane >> 5, subl = lane & 31;      // subl*2, subl*2+1 channels
  float zg[4][2] = {{0,0},{0,0},{0,0},{0,0}};
  float gg[2] = {0,0}, ssv[2] = {0,0};
  int e0 = offs[node], e1 = e0 + cnt[node];
  #pragma unroll 2
  for(int e = e0 + half; e < e1; e += 2){
    int s = csr[e];
    float4 w4 = *(const float4*)&wvE[(size_t)e*4];
    float ds = dis[s];
    unsigned int u = *(const unsigned int*)&xb[(size_t)s*64 + subl*2];
    float xl = bflo(u), xh = bfhi(u);
    zg[0][0] = fmaf(w4.x, xl, zg[0][0]); zg[0][1] = fmaf(w4.x, xh, zg[0][1]);
    zg[1][0] = fmaf(w4.y, xl, zg[1][0]); zg[1][1] = fmaf(w4.y, xh, zg[1][1]);
    zg[2][0] = fmaf(w4.z, xl, zg[2][0]); zg[2][1] = fmaf(w4.z, xh, zg[2][1]);
    zg[3][0] = fmaf(w4.w, xl, zg[3][0]); zg[3][1] = fmaf(w4.w, xh, zg[3][1]);
    gg[0] = fmaf(ds, xl, gg[0]); gg[1] = fmaf(ds, xh, gg[1]);
    ssv[0] += xl; ssv[1] += xh;
  }
  #pragma unroll
  for(int h = 0; h < 4; h++){
    zg[h][0] += __shfl_xor(zg[h][0], 32, 64);
    zg[h][1] += __shfl_xor(zg[h][1], 32, 64);
  }
  gg[0] += __shfl_xor(gg[0], 32, 64); gg[1] += __shfl_xor(gg[1], 32, 64);
  ssv[0] += __shfl_xor(ssv[0], 32, 64); ssv[1] += __shfl_xor(ssv[1], 32, 64);
  if(half == 0){
    unsigned int un = *(const unsigned int*)&xb[(size_t)node*64 + subl*2];
    float xl = bflo(un), xh = bfhi(un);
    float4 ws4 = *(const float4*)&wvS[node*4];
    float4 rd4 = *(const float4*)&rden[node*4];
    unsigned int* zp = (unsigned int*)&z[(size_t)node*256 + subl*2];
    zp[0]   = pack2((zg[0][0] + ws4.x*xl)*rd4.x, (zg[0][1] + ws4.x*xh)*rd4.x);
    zp[32]  = pack2((zg[1][0] + ws4.y*xl)*rd4.y, (zg[1][1] + ws4.y*xh)*rd4.y);
    zp[64]  = pack2((zg[2][0] + ws4.z*xl)*rd4.z, (zg[2][1] + ws4.z*xh)*rd4.z);
    zp[96]  = pack2((zg[3][0] + ws4.w*xl)*rd4.w, (zg[3][1] + ws4.w*xh)*rd4.w);
    float dc = dis[node], ic = invc[node];
    *(unsigned int*)&agcnx[(size_t)node*64 + subl*2] =
        pack2(dc*fmaf(dc, xl, gg[0]), dc*fmaf(dc, xh, gg[1]));
    *(unsigned int*)&asagex[(size_t)node*64 + subl*2] = pack2(ssv[0]*ic, ssv[1]*ic);
  }
}

// ---------------- layer-2 one-pass pre-aggregation over a1 / s1 / h2 ----------------
__global__ void k_aggf(const unsigned short* __restrict__ a1, const unsigned short* __restrict__ s1,
                       const unsigned short* __restrict__ h2,
                       const float* __restrict__ wvE, const float* __restrict__ rden,
                       const float* __restrict__ wvS,
                       const float* __restrict__ dis, const float* __restrict__ invc,
                       const int* __restrict__ offs, const int* __restrict__ cnt,
                       const int* __restrict__ csr,
                       unsigned short* __restrict__ A2agg, unsigned short* __restrict__ S2agg,
                       unsigned short* __restrict__ T2, int N){
  int node = blockIdx.x*4 + (threadIdx.x >> 6);
  int lane = threadIdx.x & 63;
  if(node >= N) return;
  int half = lane >> 5, subl = lane & 31;
  float aa[2] = {0,0}, ss[2] = {0,0}, tt[2] = {0,0};
  int e0 = offs[node], e1 = e0 + cnt[node];
  #pragma unroll 2
  for(int e = e0 + half; e < e1; e += 2){
    int s = csr[e];
    float ds = dis[s];
    float wv = wvE[e];
    unsigned int ua = *(const unsigned int*)&a1[(size_t)s*64 + subl*2];
    unsigned int us = *(const unsigned int*)&s1[(size_t)s*64 + subl*2];
    unsigned int uh = *(const unsigned int*)&h2[(size_t)s*64 + subl*2];
    aa[0] = fmaf(ds, bflo(ua), aa[0]); aa[1] = fmaf(ds, bfhi(ua), aa[1]);
    ss[0] += bflo(us); ss[1] += bfhi(us);
    tt[0] = fmaf(wv, bflo(uh), tt[0]); tt[1] = fmaf(wv, bfhi(uh), tt[1]);
  }
  aa[0] += __shfl_xor(aa[0], 32, 64); aa[1] += __shfl_xor(aa[1], 32, 64);
  ss[0] += __shfl_xor(ss[0], 32, 64); ss[1] += __shfl_xor(ss[1], 32, 64);
  tt[0] += __shfl_xor(tt[0], 32, 64); tt[1] += __shfl_xor(tt[1], 32, 64);
  if(half == 0){
    unsigned int uan = *(const unsigned int*)&a1[(size_t)node*64 + subl*2];
    unsigned int uhn = *(const unsigned int*)&h2[(size_t)node*64 + subl*2];
    float dc = dis[node], ic = invc[node];
    float rd = rden[node], wss = wvS[node];
    *(unsigned int*)&A2agg[(size_t)node*64 + subl*2] =
        pack2(dc*fmaf(dc, bflo(uan), aa[0]), dc*fmaf(dc, bfhi(uan), aa[1]));
    *(unsigned int*)&S2agg[(size_t)node*64 + subl*2] = pack2(ss[0]*ic, ss[1]*ic);
    *(unsigned int*)&T2[(size_t)node*64 + subl*2] =
        pack2(fmaf(wss, bflo(uhn), tt[0])*rd, fmaf(wss, bfhi(uhn), tt[1])*rd);
  }
}

// ---------------- MFMA bf16 matmul, LDS-free B + coalesced epilogue via LDS tile ----------------
// ep: 1 = BN+relu; 3 = sage(+bias, row L2-norm, relu). 64-col output only.
struct MME {
  const unsigned short* A; const unsigned short* WT;    // WT row stride = K
  const unsigned short* A2; const unsigned short* WT2;  // optional 2nd segment, K2=64
  unsigned short* C;
  const float* b; const float* p1; const float* p2;
  int lda, ldc, K, ep;
};
struct MMP { MME e[4]; int N; };

__global__ __launch_bounds__(256) void k_mm_mfma(MMP p){
  __shared__ unsigned short T[64*72];   // pitch 72 shorts (144B, 16B-aligned rows)
  MME m = p.e[blockIdx.y];
  const int N = p.N, K = m.K;
  int tid = threadIdx.x;
  int w = tid >> 6, lane = tid & 63, quad = lane >> 4, m16 = lane & 15;
  int rowa = blockIdx.x*64 + w*16 + m16;
  int rowc = rowa < N ? rowa : N - 1;
  f32x4 acc[4];
  #pragma unroll
  for(int t = 0; t < 4; t++){ acc[t][0]=0.f; acc[t][1]=0.f; acc[t][2]=0.f; acc[t][3]=0.f; }
  for(int kc = 0; kc < K; kc += 64){
    bf16x8 a0 = *(const bf16x8*)&m.A[(size_t)rowc*m.lda + kc + quad*8];
    bf16x8 a1 = *(const bf16x8*)&m.A[(size_t)rowc*m.lda + kc + 32 + quad*8];
    #pragma unroll
    for(int t = 0; t < 4; t++){
      const unsigned short* wr = &m.WT[(size_t)(t*16 + m16)*K + kc + quad*8];
      acc[t] = __builtin_amdgcn_mfma_f32_16x16x32_bf16(a0, *(const bf16x8*)wr, acc[t], 0, 0, 0);
      acc[t] = __builtin_amdgcn_mfma_f32_16x16x32_bf16(a1, *(const bf16x8*)(wr+32), acc[t], 0, 0, 0);
    }
  }
  if(m.A2){
    bf16x8 a0 = *(const bf16x8*)&m.A2[(size_t)rowc*64 + quad*8];
    bf16x8 a1 = *(const bf16x8*)&m.A2[(size_t)rowc*64 + 32 + quad*8];
    #pragma unroll
    for(int t = 0; t < 4; t++){
      const unsigned short* wr = &m.WT2[(size_t)(t*16 + m16)*64 + quad*8];
      acc[t] = __builtin_amdgcn_mfma_f32_16x16x32_bf16(a0, *(const bf16x8*)wr, acc[t], 0, 0, 0);
      acc[t] = __builtin_amdgcn_mfma_f32_16x16x32_bf16(a1, *(const bf16x8*)(wr+32), acc[t], 0, 0, 0);
    }
  }
  if(m.ep == 3){
    float v[4][4], n2[4] = {0,0,0,0};
    #pragma unroll
    for(int t = 0; t < 4; t++){
      float bv = m.b[t*16 + m16];
      #pragma unroll
      for(int r = 0; r < 4; r++){ v[t][r] = acc[t][r] + bv; n2[r] = fmaf(v[t][r], v[t][r], n2[r]); }
    }
    #pragma unroll
    for(int d = 8; d >= 1; d >>= 1){
      #pragma unroll
      for(int r = 0; r < 4; r++) n2[r] += __shfl_xor(n2[r], d, 64);
    }
    #pragma unroll
    for(int r = 0; r < 4; r++){
      float inv = 1.0f / fmaxf(sqrtf(n2[r]), 1e-12f);
      int rowl = w*16 + quad*4 + r;
      #pragma unroll
      for(int t = 0; t < 4; t++)
        T[rowl*72 + t*16 + m16] = f2bf(fmaxf(v[t][r]*inv, 0.f));
    }
  } else { // ep==1 BN+relu
    #pragma unroll
    for(int t = 0; t < 4; t++){
      int colc = t*16 + m16;
      float bv = m.b[colc];
      float gm = m.p1[colc]*rsqrtf(1.0f + 1e-5f);
      float be = m.p2[colc];
      #pragma unroll
      for(int r = 0; r < 4; r++){
        int rowl = w*16 + quad*4 + r;
        T[rowl*72 + colc] = f2bf(fmaxf((acc[t][r] + bv)*gm + be, 0.f));
      }
    }
  }
  __syncthreads();
  int rr = tid >> 2, c0 = (tid & 3)*16;
  int rowg = blockIdx.x*64 + rr;
  if(rowg < N){
    bf16x8 v0 = *(const bf16x8*)&T[rr*72 + c0];
    bf16x8 v1 = *(const bf16x8*)&T[rr*72 + c0 + 8];
    *(bf16x8*)&m.C[(size_t)rowg*m.ldc + c0] = v0;
    *(bf16x8*)&m.C[(size_t)rowg*m.ldc + c0 + 8] = v1;
  }
}

// ---------------- fused GAT: z @ W1 (block-diag heads) + ELU -> LDS -> @ W2 + attdot ----------------
__global__ __launch_bounds__(256) void k_mm_gat(
    const unsigned short* __restrict__ z, const unsigned short* __restrict__ WT1,
    const float* __restrict__ b1,
    const unsigned short* __restrict__ WT2,
    const float* __restrict__ as2, const float* __restrict__ ad2,
    unsigned short* __restrict__ h2, float* __restrict__ asrc2, float* __restrict__ adst2,
    int N){
  __shared__ unsigned short G[64*264];   // gath tile, pitch 264 shorts
  int tid = threadIdx.x;
  int w = tid >> 6, lane = tid & 63, quad = lane >> 4, m16 = lane & 15;
  int row0 = blockIdx.x*64;
  int rowa = row0 + w*16 + m16;
  int rowc = rowa < N ? rowa : N - 1;
  // mm1: per head, 64x64 block-diagonal
  for(int hd = 0; hd < 4; hd++){
    f32x4 acc[4];
    #pragma unroll
    for(int t = 0; t < 4; t++){ acc[t][0]=0.f; acc[t][1]=0.f; acc[t][2]=0.f; acc[t][3]=0.f; }
    bf16x8 a0 = *(const bf16x8*)&z[(size_t)rowc*256 + hd*64 + quad*8];
    bf16x8 a1 = *(const bf16x8*)&z[(size_t)rowc*256 + hd*64 + 32 + quad*8];
    #pragma unroll
    for(int t = 0; t < 4; t++){
      const unsigned short* wr = &WT1[(size_t)(hd*64 + t*16 + m16)*64 + quad*8];
      acc[t] = __builtin_amdgcn_mfma_f32_16x16x32_bf16(a0, *(const bf16x8*)wr, acc[t], 0, 0, 0);
      acc[t] = __builtin_amdgcn_mfma_f32_16x16x32_bf16(a1, *(const bf16x8*)(wr+32), acc[t], 0, 0, 0);
    }
    #pragma unroll
    for(int t = 0; t < 4; t++){
      int col = hd*64 + t*16 + m16;
      float bv = b1[col];
      #pragma unroll
      for(int r = 0; r < 4; r++){
        int rowl = w*16 + quad*4 + r;
        G[rowl*264 + col] = f2bf(elu1(acc[t][r] + bv));
      }
    }
  }
  __syncthreads();
  // mm2: h2 = gath @ W2, K=256, A-frags from LDS
  f32x4 acc2[4];
  #pragma unroll
  for(int t = 0; t < 4; t++){ acc2[t][0]=0.f; acc2[t][1]=0.f; acc2[t][2]=0.f; acc2[t][3]=0.f; }
  for(int kc = 0; kc < 256; kc += 64){
    bf16x8 a0 = *(const bf16x8*)&G[(w*16 + m16)*264 + kc + quad*8];
    bf16x8 a1 = *(const bf16x8*)&G[(w*16 + m16)*264 + kc + 32 + quad*8];
    #pragma unroll
    for(int t = 0; t < 4; t++){
      const unsigned short* wr = &WT2[(size_t)(t*16 + m16)*256 + kc + quad*8];
      acc2[t] = __builtin_amdgcn_mfma_f32_16x16x32_bf16(a0, *(const bf16x8*)wr, acc2[t], 0, 0, 0);
      acc2[t] = __builtin_amdgcn_mfma_f32_16x16x32_bf16(a1, *(const bf16x8*)(wr+32), acc2[t], 0, 0, 0);
    }
  }
  // folded attention dots
  {
    float ps[4] = {0,0,0,0}, pd[4] = {0,0,0,0};
    #pragma unroll
    for(int t = 0; t < 4; t++){
      int col = t*16 + m16;
      float a_ = as2[col], d_ = ad2[col];
      #pragma unroll
      for(int r = 0; r < 4; r++){ ps[r] = fmaf(acc2[t][r], a_, ps[r]); pd[r] = fmaf(acc2[t][r], d_, pd[r]); }
    }
    #pragma unroll
    for(int d = 8; d >= 1; d >>= 1){
      #pragma unroll
      for(int r = 0; r < 4; r++){ ps[r] += __shfl_xor(ps[r], d, 64); pd[r] += __shfl_xor(pd[r], d, 64); }
    }
    if(m16 == 0){
      #pragma unroll
      for(int r = 0; r < 4; r++){
        int ro = row0 + w*16 + quad*4 + r;
        if(ro < N){ asrc2[ro] = ps[r]; adst2[ro] = pd[r]; }
      }
    }
  }
  // h2 store via LDS tile (reuse G, pitch 264)
  __syncthreads();
  #pragma unroll
  for(int t = 0; t < 4; t++){
    #pragma unroll
    for(int r = 0; r < 4; r++){
      int rowl = w*16 + quad*4 + r;
      G[rowl*264 + t*16 + m16] = f2bf(acc2[t][r]);
    }
  }
  __syncthreads();
  int rr = tid >> 2, c0 = (tid & 3)*16;
  int rowg = row0 + rr;
  if(rowg < N){
    bf16x8 v0 = *(const bf16x8*)&G[rr*264 + c0];
    bf16x8 v1 = *(const bf16x8*)&G[rr*264 + c0 + 8];
    *(bf16x8*)&h2[(size_t)rowg*64 + c0] = v0;
    *(bf16x8*)&h2[(size_t)rowg*64 + c0 + 8] = v1;
  }
}

// ---------------- final: GCN2 mm + SAGE2 dual mm + L2norm + GAT2 add + gate combine ----------------
__global__ __launch_bounds__(256) void k_mm_final(
    const unsigned short* __restrict__ A2agg, const unsigned short* __restrict__ WTg,
    const float* __restrict__ gcn_b2,
    const unsigned short* __restrict__ S2agg, const unsigned short* __restrict__ WTl,
    const float* __restrict__ bl2,
    const unsigned short* __restrict__ s1, const unsigned short* __restrict__ WTr,
    const unsigned short* __restrict__ T2, const float* __restrict__ gat_b2,
    const float* __restrict__ gatew, float* __restrict__ out, int N){
  __shared__ float Tf[64*76];   // fp32 tile, pitch 76 (304B, 16B-aligned rows)
  int tid = threadIdx.x;
  int w = tid >> 6, lane = tid & 63, quad = lane >> 4, m16 = lane & 15;
  int rowa = blockIdx.x*64 + w*16 + m16;
  int rowc = rowa < N ? rowa : N - 1;
  f32x4 accg[4], accs[4];
  #pragma unroll
  for(int t = 0; t < 4; t++){
    accg[t][0]=0.f; accg[t][1]=0.f; accg[t][2]=0.f; accg[t][3]=0.f;
    accs[t][0]=0.f; accs[t][1]=0.f; accs[t][2]=0.f; accs[t][3]=0.f;
  }
  {
    bf16x8 a0 = *(const bf16x8*)&A2agg[(size_t)rowc*64 + quad*8];
    bf16x8 a1 = *(const bf16x8*)&A2agg[(size_t)rowc*64 + 32 + quad*8];
    bf16x8 c0 = *(const bf16x8*)&S2agg[(size_t)rowc*64 + quad*8];
    bf16x8 c1 = *(const bf16x8*)&S2agg[(size_t)rowc*64 + 32 + quad*8];
    bf16x8 d0 = *(const bf16x8*)&s1[(size_t)rowc*64 + quad*8];
    bf16x8 d1 = *(const bf16x8*)&s1[(size_t)rowc*64 + 32 + quad*8];
    #pragma unroll
    for(int t = 0; t < 4; t++){
      const unsigned short* wg = &WTg[(size_t)(t*16 + m16)*64 + quad*8];
      const unsigned short* wl = &WTl[(size_t)(t*16 + m16)*64 + quad*8];
      const unsigned short* wr = &WTr[(size_t)(t*16 + m16)*64 + quad*8];
      accg[t] = __builtin_amdgcn_mfma_f32_16x16x32_bf16(a0, *(const bf16x8*)wg, accg[t], 0, 0, 0);
      accg[t] = __builtin_amdgcn_mfma_f32_16x16x32_bf16(a1, *(const bf16x8*)(wg+32), accg[t], 0, 0, 0);
      accs[t] = __builtin_amdgcn_mfma_f32_16x16x32_bf16(c0, *(const bf16x8*)wl, accs[t], 0, 0, 0);
      accs[t] = __builtin_amdgcn_mfma_f32_16x16x32_bf16(c1, *(const bf16x8*)(wl+32), accs[t], 0, 0, 0);
      accs[t] = __builtin_amdgcn_mfma_f32_16x16x32_bf16(d0, *(const bf16x8*)wr, accs[t], 0, 0, 0);
      accs[t] = __builtin_amdgcn_mfma_f32_16x16x32_bf16(d1, *(const bf16x8*)(wr+32), accs[t], 0, 0, 0);
    }
  }
  float w0 = gatew[0], w1 = gatew[1], w2 = gatew[2];
  float vs[4][4], n2[4] = {0,0,0,0};
  #pragma unroll
  for(int t = 0; t < 4; t++){
    float bsv = bl2[t*16 + m16];
    #pragma unroll
    for(int r = 0; r < 4; r++){ vs[t][r] = accs[t][r] + bsv; n2[r] = fmaf(vs[t][r], vs[t][r], n2[r]); }
  }
  #pragma unroll
  for(int d = 8; d >= 1; d >>= 1){
    #pragma unroll
    for(int r = 0; r < 4; r++) n2[r] += __shfl_xor(n2[r], d, 64);
  }
  #pragma unroll
  for(int r = 0; r < 4; r++){
    float inv = 1.0f / fmaxf(sqrtf(n2[r]), 1e-12f);
    int rowl = w*16 + quad*4 + r;
    int ro = blockIdx.x*64 + rowl;
    int roc = ro < N ? ro : N - 1;
    #pragma unroll
    for(int t = 0; t < 4; t++){
      int col = t*16 + m16;
      float t2 = bflo((unsigned int)T2[(size_t)roc*64 + col]);
      Tf[rowl*76 + col] = w0*(accg[t][r] + gcn_b2[col]) + w1*(t2 + gat_b2[col]) + w2*vs[t][r]*inv;
    }
  }
  __syncthreads();
  int rr = tid >> 2, c0 = (tid & 3)*16;
  int rowg = blockIdx.x*64 + rr;
  if(rowg < N){
    #pragma unroll
    for(int i = 0; i < 4; i++){
      float4 v = *(const float4*)&Tf[rr*76 + c0 + i*4];
      *(float4*)&out[(size_t)rowg*64 + c0 + i*4] = v;
    }
  }
}

// ---------------- host ----------------
extern "C" void kernel_launch(void* const* d_in, const int* in_sizes, int n_in,
                              void* d_out, int out_size, void* d_ws, size_t ws_size,
                              hipStream_t stream){
  const float* x        = (const float*)d_in[0];
  const int*   ei       = (const int*)d_in[1];
  const int*   row      = ei;
  const int*   col      = ei + NE;
  const float* gate_w1  = (const float*)d_in[2];
  const float* gate_b1  = (const float*)d_in[3];
  const float* gate_w2  = (const float*)d_in[4];
  const float* gate_b2  = (const float*)d_in[5];
  const float* gcn_w1   = (const float*)d_in[6];
  const float* gcn_b1   = (const float*)d_in[7];
  const float* bn_gamma = (const float*)d_in[8];
  const float* bn_beta  = (const float*)d_in[9];
  const float* gcn_w2   = (const float*)d_in[10];
  const float* gcn_b2   = (const float*)d_in[11];
  const float* gat_w1   = (const float*)d_in[12];
  const float* gat_as1  = (const float*)d_in[13];
  const float* gat_ad1  = (const float*)d_in[14];
  const float* gat_b1   = (const float*)d_in[15];
  const float* gat_w2   = (const float*)d_in[16];
  const float* gat_as2  = (const float*)d_in[17];
  const float* gat_ad2  = (const float*)d_in[18];
  const float* gat_b2   = (const float*)d_in[19];
  const float* sage_wl1 = (const float*)d_in[20];
  const float* sage_bl1 = (const float*)d_in[21];
  const float* sage_wr1 = (const float*)d_in[22];
  const float* sage_wl2 = (const float*)d_in[23];
  const float* sage_bl2 = (const float*)d_in[24];
  const float* sage_wr2 = (const float*)d_in[25];
  float* out = (float*)d_out;

  char* wp = (char*)d_ws;
  auto alloc = [&](size_t bytes)->char*{ char* p = wp; wp += (bytes + 255) & ~(size_t)255; return p; };
  // zero-init region (contiguous): cnt, cursor, gsum, total
  int*   cnt    = (int*)  alloc((size_t)NN*4);
  int*   cursor = (int*)  alloc((size_t)NN*4);
  float* gsum   = (float*)alloc(64*4);
  int*   total  = (int*)  alloc(256);
  size_t zbytes = (size_t)(wp - (char*)cnt);
  int*   offs   = (int*)  alloc((size_t)NN*4);
  int*   csr    = (int*)  alloc((size_t)NE*4);
  float* dis    = (float*)alloc((size_t)NN*4);
  float* invc   = (float*)alloc((size_t)NN*4);
  float* gatew  = (float*)alloc(16);
  float* wsd    = (float*)alloc(64*8*4);
  float* asrc1  = (float*)alloc((size_t)NN*4*4);
  float* adst1  = (float*)alloc((size_t)NN*4*4);
  float* asrc2  = (float*)alloc((size_t)NN*4);
  float* adst2  = (float*)alloc((size_t)NN*4);
  float* wvE1   = (float*)alloc((size_t)NE*4*4);
  float* rden1  = (float*)alloc((size_t)NN*4*4);
  float* wvS1   = (float*)alloc((size_t)NN*4*4);
  float* wvE2   = (float*)alloc((size_t)NE*4);
  float* rden2  = (float*)alloc((size_t)NN*4);
  float* wvS2   = (float*)alloc((size_t)NN*4);
  // packed bf16 transposed weights
  unsigned short* WT_gcn1 = (unsigned short*)alloc(64*64*2);
  unsigned short* WT_sl1  = (unsigned short*)alloc(64*64*2);
  unsigned short* WT_sr1  = (unsigned short*)alloc(64*64*2);
  unsigned short* WT_gat1 = (unsigned short*)alloc(256*64*2);
  unsigned short* WT_gat2 = (unsigned short*)alloc(64*256*2);
  unsigned short* WT_gcn2 = (unsigned short*)alloc(64*64*2);
  unsigned short* WT_sl2  = (unsigned short*)alloc(64*64*2);
  unsigned short* WT_sr2  = (unsigned short*)alloc(64*64*2);
  unsigned short* xb     = (unsigned short*)alloc((size_t)NN*64*2);
  unsigned short* z      = (unsigned short*)alloc((size_t)NN*256*2);
  unsigned short* agcnx  = (unsigned short*)alloc((size_t)NN*64*2);
  unsigned short* asagex = (unsigned short*)alloc((size_t)NN*64*2);
  unsigned short* a1     = (unsigned short*)alloc((size_t)NN*64*2);
  unsigned short* s1     = (unsigned short*)alloc((size_t)NN*64*2);
  unsigned short* h2     = (unsigned short*)alloc((size_t)NN*64*2);
  unsigned short* A2agg  = (unsigned short*)alloc((size_t)NN*64*2);
  unsigned short* S2agg  = (unsigned short*)alloc((size_t)NN*64*2);
  unsigned short* T2     = (unsigned short*)alloc((size_t)NN*64*2);

  hipMemsetAsync(cnt, 0, zbytes, stream);

  const int gN  = (NN + 63) / 64;   // 782
  const int g4  = NN / 4;           // 12500
  const int g16 = NN / 16;          // 3125
  const int gA  = (NN + 255) / 256; // 196

  // pack weights (tiny)
  {
    PKP p = {};
    p.e[0] = {gcn_w1,   WT_gcn1, 64,  64};
    p.e[1] = {sage_wl1, WT_sl1,  64,  64};
    p.e[2] = {sage_wr1, WT_sr1,  64,  64};
    p.e[3] = {gat_w1,   WT_gat1, 256, 64};
    p.e[4] = {gat_w2,   WT_gat2, 64,  256};
    p.e[5] = {gcn_w2,   WT_gcn2, 64,  64};
    p.e[6] = {sage_wl2, WT_sl2,  64,  64};
    p.e[7] = {sage_wr2, WT_sr2,  64,  64};
    k_pack<<<8, 256, 0, stream>>>(p);
  }

  k_count<<<(NE+255)/256, 256, 0, stream>>>(col, cnt, NE);
  k_alloc<<<gA, 256, 0, stream>>>(cnt, offs, dis, invc, total, NN);
  k_fill <<<(NE+255)/256, 256, 0, stream>>>(row, col, offs, cursor, csr, NE);
  k_castsum<<<256, 256, 0, stream>>>(x, xb, gsum, NN);
  k_gate  <<<1, 64, 0, stream>>>(gsum, gate_w1, gate_b1, gate_w2, gate_b2, gatew);
  k_fold1 <<<1, 256, 0, stream>>>(gat_w1, gat_as1, gat_ad1, wsd);
  k_attdotx<<<g16, 256, 0, stream>>>(xb, wsd, asrc1, adst1, NN);
  k_edgew1<<<g4, 256, 0, stream>>>(asrc1, adst1, offs, cnt, csr, wvE1, rden1, wvS1, NN);

  // ---- layer-1 one-pass pre-aggregation over xb ----
  k_aggx<<<g4, 256, 0, stream>>>(xb, wvE1, rden1, wvS1, dis, invc, offs, cnt, csr,
                                 z, agcnx, asagex, NN);

  // ---- layer-1 GCN + SAGE matmuls (coalesced epilogue) ----
  {
    MMP p = {};
    p.N = NN;
    p.e[0] = {agcnx, WT_gcn1, nullptr, nullptr, a1, gcn_b1, bn_gamma, bn_beta, 64, 64, 64, 1};
    p.e[1] = {asagex, WT_sl1, xb, WT_sr1, s1, sage_bl1, nullptr, nullptr, 64, 64, 64, 3};
    k_mm_mfma<<<dim3(gN,2), 256, 0, stream>>>(p);
  }

  // ---- fused GAT1 + GAT2 matmul (gath never leaves LDS) ----
  k_mm_gat<<<gN, 256, 0, stream>>>(z, WT_gat1, gat_b1, WT_gat2, gat_as2, gat_ad2,
                                   h2, asrc2, adst2, NN);
  k_edgew2<<<g4, 256, 0, stream>>>(asrc2, adst2, offs, cnt, csr, wvE2, rden2, wvS2, NN);

  // ---- layer-2 one-pass pre-aggregation ----
  k_aggf<<<g4, 256, 0, stream>>>(a1, s1, h2, wvE2, rden2, wvS2, dis, invc,
                                 offs, cnt, csr, A2agg, S2agg, T2, NN);

  // ---- final matmuls + gate combine (coalesced epilogue) ----
  k_mm_final<<<gN, 256, 0, stream>>>(A2agg, WT_gcn2, gcn_b2, S2agg, WT_sl2, sage_bl2,
                                     s1, WT_sr2, T2, gat_b2, gatew, out, NN);
}

// Round 11
// 385.430 us; speedup vs baseline: 1.0366x; 1.0190x over previous
//
#include <hip/hip_runtime.h>
#include <hip/hip_bf16.h>
#include <math.h>

#define NN 50000
#define NE 400000

typedef __attribute__((ext_vector_type(8))) short bf16x8;
typedef __attribute__((ext_vector_type(4))) float f32x4;

// ---------------- helpers ----------------
__device__ __forceinline__ float lrelu(float v){ return v > 0.f ? v : 0.2f*v; }
__device__ __forceinline__ float elu1(float v){ return v > 0.f ? v : expm1f(v); }
__device__ __forceinline__ float bflo(unsigned int u){ return __uint_as_float(u << 16); }
__device__ __forceinline__ float bfhi(unsigned int u){ return __uint_as_float(u & 0xffff0000u); }
__device__ __forceinline__ unsigned short f2bf(float f){
  __hip_bfloat16 h = __float2bfloat16(f);
  return *(unsigned short*)&h;
}
__device__ __forceinline__ unsigned int pack2(float lo, float hi){
  return (unsigned int)f2bf(lo) | ((unsigned int)f2bf(hi) << 16);
}

// ---------------- CSR build ----------------
__global__ void k_count(const int* __restrict__ col, int* __restrict__ cnt, int E){
  int e = blockIdx.x*blockDim.x + threadIdx.x;
  if(e < E) atomicAdd(&cnt[col[e]], 1);
}

__global__ void k_alloc(const int* __restrict__ cnt, int* __restrict__ offs,
                        float* __restrict__ dis, float* __restrict__ invc,
                        int* __restrict__ total, int N){
  int i = blockIdx.x*blockDim.x + threadIdx.x;
  int lane = threadIdx.x & 63;
  int v = (i < N) ? cnt[i] : 0;
  int x = v;
  #pragma unroll
  for(int d = 1; d < 64; d <<= 1){ int t = __shfl_up(x, d, 64); if(lane >= d) x += t; }
  int base = 0;
  if(lane == 63 && x > 0) base = atomicAdd(total, x);
  base = __shfl(base, 63, 64);
  if(i < N){
    offs[i] = base + x - v;
    dis[i]  = 1.0f / sqrtf((float)(v + 1));
    invc[i] = 1.0f / fmaxf((float)v, 1.0f);
  }
}

__global__ void k_fill(const int* __restrict__ row, const int* __restrict__ col,
                       const int* __restrict__ offs, int* __restrict__ cursor,
                       int* __restrict__ csr, int E){
  int e = blockIdx.x*blockDim.x + threadIdx.x;
  if(e < E){
    int c = col[e];
    int pos = offs[c] + atomicAdd(&cursor[c], 1);
    csr[pos] = row[e];
  }
}

// ---------------- pack weights -> bf16 transposed WT[col][k] ----------------
struct PKE { const float* W; unsigned short* T; int C, K; };
struct PKP { PKE e[8]; };
__global__ void k_pack(PKP p){
  PKE m = p.e[blockIdx.x];
  int total = m.C * m.K;
  for(int i = threadIdx.x; i < total; i += 256){
    int c = i / m.K, k = i - c*m.K;
    m.T[i] = f2bf(m.W[(size_t)k*m.C + c]);
  }
}

// ---------------- cast x -> bf16 + column sums for gate ----------------
__global__ void k_castsum(const float* __restrict__ x, unsigned short* __restrict__ xb,
                          float* __restrict__ gsum, int N){
  __shared__ float part[4][64];
  int lane = threadIdx.x & 63, w = threadIdx.x >> 6;
  float s = 0.f;
  for(int r = blockIdx.x*4 + w; r < N; r += gridDim.x*4){
    float v = x[(size_t)r*64 + lane];
    xb[(size_t)r*64 + lane] = f2bf(v);
    s += v;
  }
  part[w][lane] = s;
  __syncthreads();
  if(w == 0) atomicAdd(&gsum[lane], part[0][lane]+part[1][lane]+part[2][lane]+part[3][lane]);
}

__global__ void k_gate(const float* __restrict__ gsum,
                       const float* __restrict__ w1, const float* __restrict__ b1,
                       const float* __restrict__ w2, const float* __restrict__ b2,
                       float* __restrict__ gatew){
  __shared__ float g[64]; __shared__ float hid[64]; __shared__ float lg[3];
  int t = threadIdx.x;
  g[t] = gsum[t] * (1.0f/(float)NN);
  __syncthreads();
  float acc = b1[t];
  for(int i = 0; i < 64; i++) acc += g[i]*w1[i*64 + t];
  hid[t] = fmaxf(acc, 0.f);
  __syncthreads();
  if(t < 3){
    float a = b2[t];
    for(int j = 0; j < 64; j++) a += hid[j]*w2[j*3 + t];
    lg[t] = a;
  }
  __syncthreads();
  if(t == 0){
    float m = fmaxf(lg[0], fmaxf(lg[1], lg[2]));
    float e0 = expf(lg[0]-m), e1 = expf(lg[1]-m), e2 = expf(lg[2]-m);
    float s = e0 + e1 + e2;
    gatew[0] = e0/s; gatew[1] = e1/s; gatew[2] = e2/s;
  }
}

// ---------------- fold GAT1 attention vectors through W ----------------
__global__ void k_fold1(const float* __restrict__ w1, const float* __restrict__ as,
                        const float* __restrict__ ad, float* __restrict__ wsd){
  int t = threadIdx.x;            // 256
  int k = t & 63, h = t >> 6;
  float ssrc = 0.f, sdst = 0.f;
  for(int c = 0; c < 64; c++){
    float w = w1[k*256 + h*64 + c];
    ssrc += w * as[h*64 + c];
    sdst += w * ad[h*64 + c];
  }
  wsd[k*8 + h] = ssrc;
  wsd[k*8 + 4 + h] = sdst;
}

// ---------------- asrc1/adst1 = xb @ Wsd  (16 lanes per node) ----------------
__global__ void k_attdotx(const unsigned short* __restrict__ xb, const float* __restrict__ wsd,
                          float* __restrict__ asrc, float* __restrict__ adst, int N){
  __shared__ float ws[64*8];
  int tid = threadIdx.x;
  ws[tid] = wsd[tid];
  ws[tid + 256] = wsd[tid + 256];
  __syncthreads();
  int node = blockIdx.x*16 + (tid >> 4);
  int l = tid & 15;
  if(node >= N) return;
  uint2 u = *(const uint2*)&xb[(size_t)node*64 + l*4];
  float v0 = bflo(u.x), v1 = bfhi(u.x), v2 = bflo(u.y), v3 = bfhi(u.y);
  float s[8];
  #pragma unroll
  for(int h = 0; h < 8; h++){
    s[h] = v0*ws[(l*4+0)*8+h] + v1*ws[(l*4+1)*8+h] + v2*ws[(l*4+2)*8+h] + v3*ws[(l*4+3)*8+h];
  }
  #pragma unroll
  for(int d = 8; d >= 1; d >>= 1){
    #pragma unroll
    for(int h = 0; h < 8; h++) s[h] += __shfl_xor(s[h], d, 16);
  }
  if(l == 0){
    float4 o1; o1.x = s[0]; o1.y = s[1]; o1.z = s[2]; o1.w = s[3];
    float4 o2; o2.x = s[4]; o2.y = s[5]; o2.z = s[6]; o2.w = s[7];
    *(float4*)&asrc[node*4] = o1;
    *(float4*)&adst[node*4] = o2;
  }
}

// ---------------- layer-1 one-pass pre-aggregation over xb (edge weights inline) ----------------
__global__ void k_aggx(const unsigned short* __restrict__ xb,
                       const float* __restrict__ asrc, const float* __restrict__ adst,
                       const float* __restrict__ dis, const float* __restrict__ invc,
                       const int* __restrict__ offs, const int* __restrict__ cnt,
                       const int* __restrict__ csr,
                       unsigned short* __restrict__ z, unsigned short* __restrict__ agcnx,
                       unsigned short* __restrict__ asagex, int N){
  int node = blockIdx.x*4 + (threadIdx.x >> 6);
  int lane = threadIdx.x & 63;
  if(node >= N) return;
  int half = lane >> 5, subl = lane & 31;      // subl*2, subl*2+1 channels
  float4 ad = *(const float4*)&adst[node*4];
  float zg[4][2] = {{0,0},{0,0},{0,0},{0,0}};
  float den[4] = {0,0,0,0};
  float gg[2] = {0,0}, ssv[2] = {0,0};
  int e0 = offs[node], e1 = e0 + cnt[node];
  for(int e = e0 + half; e < e1; e += 2){
    int s = csr[e];
    float4 as = *(const float4*)&asrc[s*4];   // broadcast across the half-wave
    float ds = dis[s];
    unsigned int u = *(const unsigned int*)&xb[(size_t)s*64 + subl*2];
    float w0 = expf(lrelu(as.x + ad.x));
    float w1 = expf(lrelu(as.y + ad.y));
    float w2 = expf(lrelu(as.z + ad.z));
    float w3 = expf(lrelu(as.w + ad.w));
    den[0] += w0; den[1] += w1; den[2] += w2; den[3] += w3;
    float xl = bflo(u), xh = bfhi(u);
    zg[0][0] = fmaf(w0, xl, zg[0][0]); zg[0][1] = fmaf(w0, xh, zg[0][1]);
    zg[1][0] = fmaf(w1, xl, zg[1][0]); zg[1][1] = fmaf(w1, xh, zg[1][1]);
    zg[2][0] = fmaf(w2, xl, zg[2][0]); zg[2][1] = fmaf(w2, xh, zg[2][1]);
    zg[3][0] = fmaf(w3, xl, zg[3][0]); zg[3][1] = fmaf(w3, xh, zg[3][1]);
    gg[0] = fmaf(ds, xl, gg[0]); gg[1] = fmaf(ds, xh, gg[1]);
    ssv[0] += xl; ssv[1] += xh;
  }
  #pragma unroll
  for(int h = 0; h < 4; h++){
    zg[h][0] += __shfl_xor(zg[h][0], 32, 64);
    zg[h][1] += __shfl_xor(zg[h][1], 32, 64);
    den[h]   += __shfl_xor(den[h],   32, 64);
  }
  gg[0] += __shfl_xor(gg[0], 32, 64); gg[1] += __shfl_xor(gg[1], 32, 64);
  ssv[0] += __shfl_xor(ssv[0], 32, 64); ssv[1] += __shfl_xor(ssv[1], 32, 64);
  if(half == 0){
    unsigned int un = *(const unsigned int*)&xb[(size_t)node*64 + subl*2];
    float xl = bflo(un), xh = bfhi(un);
    float4 asl = *(const float4*)&asrc[node*4];
    float ws0 = expf(lrelu(asl.x + ad.x));
    float ws1 = expf(lrelu(asl.y + ad.y));
    float ws2 = expf(lrelu(asl.z + ad.z));
    float ws3 = expf(lrelu(asl.w + ad.w));
    float rd0 = 1.0f/(den[0] + ws0), rd1 = 1.0f/(den[1] + ws1);
    float rd2 = 1.0f/(den[2] + ws2), rd3 = 1.0f/(den[3] + ws3);
    unsigned int* zp = (unsigned int*)&z[(size_t)node*256 + subl*2];
    zp[0]  = pack2((zg[0][0] + ws0*xl)*rd0, (zg[0][1] + ws0*xh)*rd0);
    zp[32] = pack2((zg[1][0] + ws1*xl)*rd1, (zg[1][1] + ws1*xh)*rd1);
    zp[64] = pack2((zg[2][0] + ws2*xl)*rd2, (zg[2][1] + ws2*xh)*rd2);
    zp[96] = pack2((zg[3][0] + ws3*xl)*rd3, (zg[3][1] + ws3*xh)*rd3);
    float dc = dis[node], ic = invc[node];
    *(unsigned int*)&agcnx[(size_t)node*64 + subl*2] =
        pack2(dc*fmaf(dc, xl, gg[0]), dc*fmaf(dc, xh, gg[1]));
    *(unsigned int*)&asagex[(size_t)node*64 + subl*2] = pack2(ssv[0]*ic, ssv[1]*ic);
  }
}

// ---------------- layer-2 one-pass pre-aggregation (edge weights inline) ----------------
__global__ void k_aggf(const unsigned short* __restrict__ a1, const unsigned short* __restrict__ s1,
                       const unsigned short* __restrict__ h2,
                       const float* __restrict__ asrc2, const float* __restrict__ adst2,
                       const float* __restrict__ dis, const float* __restrict__ invc,
                       const int* __restrict__ offs, const int* __restrict__ cnt,
                       const int* __restrict__ csr,
                       unsigned short* __restrict__ A2agg, unsigned short* __restrict__ S2agg,
                       unsigned short* __restrict__ T2, int N){
  int node = blockIdx.x*4 + (threadIdx.x >> 6);
  int lane = threadIdx.x & 63;
  if(node >= N) return;
  int half = lane >> 5, subl = lane & 31;
  float ad = adst2[node];
  float aa[2] = {0,0}, ss[2] = {0,0}, tt[2] = {0,0};
  float den = 0.f;
  int e0 = offs[node], e1 = e0 + cnt[node];
  for(int e = e0 + half; e < e1; e += 2){
    int s = csr[e];
    float ds = dis[s];
    float wv = expf(lrelu(asrc2[s] + ad));
    den += wv;
    unsigned int ua = *(const unsigned int*)&a1[(size_t)s*64 + subl*2];
    unsigned int us = *(const unsigned int*)&s1[(size_t)s*64 + subl*2];
    unsigned int uh = *(const unsigned int*)&h2[(size_t)s*64 + subl*2];
    aa[0] = fmaf(ds, bflo(ua), aa[0]); aa[1] = fmaf(ds, bfhi(ua), aa[1]);
    ss[0] += bflo(us); ss[1] += bfhi(us);
    tt[0] = fmaf(wv, bflo(uh), tt[0]); tt[1] = fmaf(wv, bfhi(uh), tt[1]);
  }
  aa[0] += __shfl_xor(aa[0], 32, 64); aa[1] += __shfl_xor(aa[1], 32, 64);
  ss[0] += __shfl_xor(ss[0], 32, 64); ss[1] += __shfl_xor(ss[1], 32, 64);
  tt[0] += __shfl_xor(tt[0], 32, 64); tt[1] += __shfl_xor(tt[1], 32, 64);
  den   += __shfl_xor(den,   32, 64);
  if(half == 0){
    unsigned int uan = *(const unsigned int*)&a1[(size_t)node*64 + subl*2];
    unsigned int uhn = *(const unsigned int*)&h2[(size_t)node*64 + subl*2];
    float dc = dis[node], ic = invc[node];
    float wss = expf(lrelu(asrc2[node] + ad));
    float rd = 1.0f/(den + wss);
    *(unsigned int*)&A2agg[(size_t)node*64 + subl*2] =
        pack2(dc*fmaf(dc, bflo(uan), aa[0]), dc*fmaf(dc, bfhi(uan), aa[1]));
    *(unsigned int*)&S2agg[(size_t)node*64 + subl*2] = pack2(ss[0]*ic, ss[1]*ic);
    *(unsigned int*)&T2[(size_t)node*64 + subl*2] =
        pack2(fmaf(wss, bflo(uhn), tt[0])*rd, fmaf(wss, bfhi(uhn), tt[1])*rd);
  }
}

// ---------------- MFMA bf16 matmul, LDS-free B + coalesced epilogue via LDS tile ----------------
// ep: 1 = BN+relu; 2 = ELU; 3 = sage(+bias, row L2-norm, relu); 4 = plain + att dots
// col0 is the single source of column offset — it indexes WT rows, C columns, and bias.
struct MME {
  const unsigned short* A; const unsigned short* WT;    // WT row stride = K
  const unsigned short* A2; const unsigned short* WT2;  // optional 2nd segment, K2=64
  unsigned short* C;
  const float* b; const float* p1; const float* p2;
  float* y1; float* y2;
  int lda, ldc, col0, K, ep;
};
struct MMP { MME e[6]; int N; };

__global__ __launch_bounds__(256) void k_mm_mfma(MMP p){
  __shared__ unsigned short T[64*72];   // 64-col tile, pitch 72 shorts
  MME m = p.e[blockIdx.y];
  const int N = p.N, K = m.K;
  int tid = threadIdx.x;
  int w = tid >> 6, lane = tid & 63, quad = lane >> 4, m16 = lane & 15;
  int rowa = blockIdx.x*64 + w*16 + m16;
  int rowc = rowa < N ? rowa : N - 1;
  f32x4 acc[4];
  #pragma unroll
  for(int t = 0; t < 4; t++){ acc[t][0]=0.f; acc[t][1]=0.f; acc[t][2]=0.f; acc[t][3]=0.f; }
  for(int kc = 0; kc < K; kc += 64){
    bf16x8 a0 = *(const bf16x8*)&m.A[(size_t)rowc*m.lda + kc + quad*8];
    bf16x8 a1 = *(const bf16x8*)&m.A[(size_t)rowc*m.lda + kc + 32 + quad*8];
    #pragma unroll
    for(int t = 0; t < 4; t++){
      const unsigned short* wr = &m.WT[(size_t)(m.col0 + t*16 + m16)*K + kc + quad*8];
      acc[t] = __builtin_amdgcn_mfma_f32_16x16x32_bf16(a0, *(const bf16x8*)wr, acc[t], 0, 0, 0);
      acc[t] = __builtin_amdgcn_mfma_f32_16x16x32_bf16(a1, *(const bf16x8*)(wr+32), acc[t], 0, 0, 0);
    }
  }
  if(m.A2){
    bf16x8 a0 = *(const bf16x8*)&m.A2[(size_t)rowc*64 + quad*8];
    bf16x8 a1 = *(const bf16x8*)&m.A2[(size_t)rowc*64 + 32 + quad*8];
    #pragma unroll
    for(int t = 0; t < 4; t++){
      const unsigned short* wr = &m.WT2[(size_t)(t*16 + m16)*64 + quad*8];
      acc[t] = __builtin_amdgcn_mfma_f32_16x16x32_bf16(a0, *(const bf16x8*)wr, acc[t], 0, 0, 0);
      acc[t] = __builtin_amdgcn_mfma_f32_16x16x32_bf16(a1, *(const bf16x8*)(wr+32), acc[t], 0, 0, 0);
    }
  }
  if(m.ep == 4){   // attention-dot fold (before tiling)
    float ps[4] = {0,0,0,0}, pd[4] = {0,0,0,0};
    #pragma unroll
    for(int t = 0; t < 4; t++){
      int col = m.col0 + t*16 + m16;
      float a_ = m.p1[col], d_ = m.p2[col];
      #pragma unroll
      for(int r = 0; r < 4; r++){ ps[r] = fmaf(acc[t][r], a_, ps[r]); pd[r] = fmaf(acc[t][r], d_, pd[r]); }
    }
    #pragma unroll
    for(int d = 8; d >= 1; d >>= 1){
      #pragma unroll
      for(int r = 0; r < 4; r++){ ps[r] += __shfl_xor(ps[r], d, 64); pd[r] += __shfl_xor(pd[r], d, 64); }
    }
    if(m16 == 0){
      #pragma unroll
      for(int r = 0; r < 4; r++){
        int ro = blockIdx.x*64 + w*16 + quad*4 + r;
        if(ro < N){ m.y1[ro] = ps[r]; m.y2[ro] = pd[r]; }
      }
    }
  }
  // epilogue -> LDS tile (local 64-col coordinates)
  if(m.ep == 3){
    float v[4][4], n2[4] = {0,0,0,0};
    #pragma unroll
    for(int t = 0; t < 4; t++){
      float bv = m.b[m.col0 + t*16 + m16];
      #pragma unroll
      for(int r = 0; r < 4; r++){ v[t][r] = acc[t][r] + bv; n2[r] = fmaf(v[t][r], v[t][r], n2[r]); }
    }
    #pragma unroll
    for(int d = 8; d >= 1; d >>= 1){
      #pragma unroll
      for(int r = 0; r < 4; r++) n2[r] += __shfl_xor(n2[r], d, 64);
    }
    #pragma unroll
    for(int r = 0; r < 4; r++){
      float inv = 1.0f / fmaxf(sqrtf(n2[r]), 1e-12f);
      int rowl = w*16 + quad*4 + r;
      #pragma unroll
      for(int t = 0; t < 4; t++)
        T[rowl*72 + t*16 + m16] = f2bf(fmaxf(v[t][r]*inv, 0.f));
    }
  } else {
    #pragma unroll
    for(int t = 0; t < 4; t++){
      int col = m.col0 + t*16 + m16;
      float bv = (m.ep == 1 || m.ep == 2) ? m.b[col] : 0.f;
      float gm = (m.ep == 1) ? m.p1[col]*rsqrtf(1.0f + 1e-5f) : 0.f;
      float be = (m.ep == 1) ? m.p2[col] : 0.f;
      #pragma unroll
      for(int r = 0; r < 4; r++){
        int rowl = w*16 + quad*4 + r;
        float val = acc[t][r];
        if(m.ep == 1)      val = fmaxf((val + bv)*gm + be, 0.f);
        else if(m.ep == 2) val = elu1(val + bv);
        T[rowl*72 + t*16 + m16] = f2bf(val);
      }
    }
  }
  __syncthreads();
  int rr = tid >> 2, c0 = (tid & 3)*16;
  int rowg = blockIdx.x*64 + rr;
  if(rowg < N){
    bf16x8 v0 = *(const bf16x8*)&T[rr*72 + c0];
    bf16x8 v1 = *(const bf16x8*)&T[rr*72 + c0 + 8];
    *(bf16x8*)&m.C[(size_t)rowg*m.ldc + m.col0 + c0] = v0;
    *(bf16x8*)&m.C[(size_t)rowg*m.ldc + m.col0 + c0 + 8] = v1;
  }
}

// ---------------- final: GCN2 mm + SAGE2 dual mm + L2norm + GAT2 add + gate combine ----------------
__global__ __launch_bounds__(256) void k_mm_final(
    const unsigned short* __restrict__ A2agg, const unsigned short* __restrict__ WTg,
    const float* __restrict__ gcn_b2,
    const unsigned short* __restrict__ S2agg, const unsigned short* __restrict__ WTl,
    const float* __restrict__ bl2,
    const unsigned short* __restrict__ s1, const unsigned short* __restrict__ WTr,
    const unsigned short* __restrict__ T2, const float* __restrict__ gat_b2,
    const float* __restrict__ gatew, float* __restrict__ out, int N){
  __shared__ float Tf[64*76];
  int tid = threadIdx.x;
  int w = tid >> 6, lane = tid & 63, quad = lane >> 4, m16 = lane & 15;
  int rowa = blockIdx.x*64 + w*16 + m16;
  int rowc = rowa < N ? rowa : N - 1;
  f32x4 accg[4], accs[4];
  #pragma unroll
  for(int t = 0; t < 4; t++){
    accg[t][0]=0.f; accg[t][1]=0.f; accg[t][2]=0.f; accg[t][3]=0.f;
    accs[t][0]=0.f; accs[t][1]=0.f; accs[t][2]=0.f; accs[t][3]=0.f;
  }
  {
    bf16x8 a0 = *(const bf16x8*)&A2agg[(size_t)rowc*64 + quad*8];
    bf16x8 a1 = *(const bf16x8*)&A2agg[(size_t)rowc*64 + 32 + quad*8];
    bf16x8 c0 = *(const bf16x8*)&S2agg[(size_t)rowc*64 + quad*8];
    bf16x8 c1 = *(const bf16x8*)&S2agg[(size_t)rowc*64 + 32 + quad*8];
    bf16x8 d0 = *(const bf16x8*)&s1[(size_t)rowc*64 + quad*8];
    bf16x8 d1 = *(const bf16x8*)&s1[(size_t)rowc*64 + 32 + quad*8];
    #pragma unroll
    for(int t = 0; t < 4; t++){
      const unsigned short* wg = &WTg[(size_t)(t*16 + m16)*64 + quad*8];
      const unsigned short* wl = &WTl[(size_t)(t*16 + m16)*64 + quad*8];
      const unsigned short* wr = &WTr[(size_t)(t*16 + m16)*64 + quad*8];
      accg[t] = __builtin_amdgcn_mfma_f32_16x16x32_bf16(a0, *(const bf16x8*)wg, accg[t], 0, 0, 0);
      accg[t] = __builtin_amdgcn_mfma_f32_16x16x32_bf16(a1, *(const bf16x8*)(wg+32), accg[t], 0, 0, 0);
      accs[t] = __builtin_amdgcn_mfma_f32_16x16x32_bf16(c0, *(const bf16x8*)wl, accs[t], 0, 0, 0);
      accs[t] = __builtin_amdgcn_mfma_f32_16x16x32_bf16(c1, *(const bf16x8*)(wl+32), accs[t], 0, 0, 0);
      accs[t] = __builtin_amdgcn_mfma_f32_16x16x32_bf16(d0, *(const bf16x8*)wr, accs[t], 0, 0, 0);
      accs[t] = __builtin_amdgcn_mfma_f32_16x16x32_bf16(d1, *(const bf16x8*)(wr+32), accs[t], 0, 0, 0);
    }
  }
  float w0 = gatew[0], w1 = gatew[1], w2 = gatew[2];
  float vs[4][4], n2[4] = {0,0,0,0};
  #pragma unroll
  for(int t = 0; t < 4; t++){
    float bsv = bl2[t*16 + m16];
    #pragma unroll
    for(int r = 0; r < 4; r++){ vs[t][r] = accs[t][r] + bsv; n2[r] = fmaf(vs[t][r], vs[t][r], n2[r]); }
  }
  #pragma unroll
  for(int d = 8; d >= 1; d >>= 1){
    #pragma unroll
    for(int r = 0; r < 4; r++) n2[r] += __shfl_xor(n2[r], d, 64);
  }
  #pragma unroll
  for(int r = 0; r < 4; r++){
    float inv = 1.0f / fmaxf(sqrtf(n2[r]), 1e-12f);
    int rowl = w*16 + quad*4 + r;
    int ro = blockIdx.x*64 + rowl;
    int roc = ro < N ? ro : N - 1;
    #pragma unroll
    for(int t = 0; t < 4; t++){
      int col = t*16 + m16;
      float t2 = bflo((unsigned int)T2[(size_t)roc*64 + col]);
      Tf[rowl*76 + col] = w0*(accg[t][r] + gcn_b2[col]) + w1*(t2 + gat_b2[col]) + w2*vs[t][r]*inv;
    }
  }
  __syncthreads();
  int rr = tid >> 2, c0 = (tid & 3)*16;
  int rowg = blockIdx.x*64 + rr;
  if(rowg < N){
    #pragma unroll
    for(int i = 0; i < 4; i++){
      float4 v = *(const float4*)&Tf[rr*76 + c0 + i*4];
      *(float4*)&out[(size_t)rowg*64 + c0 + i*4] = v;
    }
  }
}

// ---------------- host ----------------
extern "C" void kernel_launch(void* const* d_in, const int* in_sizes, int n_in,
                              void* d_out, int out_size, void* d_ws, size_t ws_size,
                              hipStream_t stream){
  const float* x        = (const float*)d_in[0];
  const int*   ei       = (const int*)d_in[1];
  const int*   row      = ei;
  const int*   col      = ei + NE;
  const float* gate_w1  = (const float*)d_in[2];
  const float* gate_b1  = (const float*)d_in[3];
  const float* gate_w2  = (const float*)d_in[4];
  const float* gate_b2  = (const float*)d_in[5];
  const float* gcn_w1   = (const float*)d_in[6];
  const float* gcn_b1   = (const float*)d_in[7];
  const float* bn_gamma = (const float*)d_in[8];
  const float* bn_beta  = (const float*)d_in[9];
  const float* gcn_w2   = (const float*)d_in[10];
  const float* gcn_b2   = (const float*)d_in[11];
  const float* gat_w1   = (const float*)d_in[12];
  const float* gat_as1  = (const float*)d_in[13];
  const float* gat_ad1  = (const float*)d_in[14];
  const float* gat_b1   = (const float*)d_in[15];
  const float* gat_w2   = (const float*)d_in[16];
  const float* gat_as2  = (const float*)d_in[17];
  const float* gat_ad2  = (const float*)d_in[18];
  const float* gat_b2   = (const float*)d_in[19];
  const float* sage_wl1 = (const float*)d_in[20];
  const float* sage_bl1 = (const float*)d_in[21];
  const float* sage_wr1 = (const float*)d_in[22];
  const float* sage_wl2 = (const float*)d_in[23];
  const float* sage_bl2 = (const float*)d_in[24];
  const float* sage_wr2 = (const float*)d_in[25];
  float* out = (float*)d_out;

  char* wp = (char*)d_ws;
  auto alloc = [&](size_t bytes)->char*{ char* p = wp; wp += (bytes + 255) & ~(size_t)255; return p; };
  // zero-init region (contiguous): cnt, cursor, gsum, total
  int*   cnt    = (int*)  alloc((size_t)NN*4);
  int*   cursor = (int*)  alloc((size_t)NN*4);
  float* gsum   = (float*)alloc(64*4);
  int*   total  = (int*)  alloc(256);
  size_t zbytes = (size_t)(wp - (char*)cnt);
  int*   offs   = (int*)  alloc((size_t)NN*4);
  int*   csr    = (int*)  alloc((size_t)NE*4);
  float* dis    = (float*)alloc((size_t)NN*4);
  float* invc   = (float*)alloc((size_t)NN*4);
  float* gatew  = (float*)alloc(16);
  float* wsd    = (float*)alloc(64*8*4);
  float* asrc1  = (float*)alloc((size_t)NN*4*4);
  float* adst1  = (float*)alloc((size_t)NN*4*4);
  float* asrc2  = (float*)alloc((size_t)NN*4);
  float* adst2  = (float*)alloc((size_t)NN*4);
  // packed bf16 transposed weights
  unsigned short* WT_gcn1 = (unsigned short*)alloc(64*64*2);
  unsigned short* WT_sl1  = (unsigned short*)alloc(64*64*2);
  unsigned short* WT_sr1  = (unsigned short*)alloc(64*64*2);
  unsigned short* WT_gat1 = (unsigned short*)alloc(256*64*2);
  unsigned short* WT_gat2 = (unsigned short*)alloc(64*256*2);
  unsigned short* WT_gcn2 = (unsigned short*)alloc(64*64*2);
  unsigned short* WT_sl2  = (unsigned short*)alloc(64*64*2);
  unsigned short* WT_sr2  = (unsigned short*)alloc(64*64*2);
  unsigned short* xb     = (unsigned short*)alloc((size_t)NN*64*2);
  unsigned short* z      = (unsigned short*)alloc((size_t)NN*256*2);
  unsigned short* agcnx  = (unsigned short*)alloc((size_t)NN*64*2);
  unsigned short* asagex = (unsigned short*)alloc((size_t)NN*64*2);
  unsigned short* a1     = (unsigned short*)alloc((size_t)NN*64*2);
  unsigned short* s1     = (unsigned short*)alloc((size_t)NN*64*2);
  unsigned short* gath   = (unsigned short*)alloc((size_t)NN*256*2);
  unsigned short* h2     = (unsigned short*)alloc((size_t)NN*64*2);
  unsigned short* A2agg  = (unsigned short*)alloc((size_t)NN*64*2);
  unsigned short* S2agg  = (unsigned short*)alloc((size_t)NN*64*2);
  unsigned short* T2     = (unsigned short*)alloc((size_t)NN*64*2);

  hipMemsetAsync(cnt, 0, zbytes, stream);

  const int gN  = (NN + 63) / 64;   // 782
  const int g4  = NN / 4;           // 12500
  const int g16 = NN / 16;          // 3125
  const int gA  = (NN + 255) / 256; // 196

  // pack weights (tiny)
  {
    PKP p = {};
    p.e[0] = {gcn_w1,   WT_gcn1, 64,  64};
    p.e[1] = {sage_wl1, WT_sl1,  64,  64};
    p.e[2] = {sage_wr1, WT_sr1,  64,  64};
    p.e[3] = {gat_w1,   WT_gat1, 256, 64};
    p.e[4] = {gat_w2,   WT_gat2, 64,  256};
    p.e[5] = {gcn_w2,   WT_gcn2, 64,  64};
    p.e[6] = {sage_wl2, WT_sl2,  64,  64};
    p.e[7] = {sage_wr2, WT_sr2,  64,  64};
    k_pack<<<8, 256, 0, stream>>>(p);
  }

  k_count<<<(NE+255)/256, 256, 0, stream>>>(col, cnt, NE);
  k_alloc<<<gA, 256, 0, stream>>>(cnt, offs, dis, invc, total, NN);
  k_fill <<<(NE+255)/256, 256, 0, stream>>>(row, col, offs, cursor, csr, NE);
  k_castsum<<<256, 256, 0, stream>>>(x, xb, gsum, NN);
  k_gate  <<<1, 64, 0, stream>>>(gsum, gate_w1, gate_b1, gate_w2, gate_b2, gatew);
  k_fold1 <<<1, 256, 0, stream>>>(gat_w1, gat_as1, gat_ad1, wsd);
  k_attdotx<<<g16, 256, 0, stream>>>(xb, wsd, asrc1, adst1, NN);

  // ---- layer-1 one-pass pre-aggregation (edge weights computed inline) ----
  k_aggx<<<g4, 256, 0, stream>>>(xb, asrc1, adst1, dis, invc, offs, cnt, csr,
                                 z, agcnx, asagex, NN);

  // ---- layer-1 matmuls: GCN + SAGE + 4 GAT head slabs, one dispatch ----
  {
    MMP p = {};
    p.N = NN;
    p.e[0] = {agcnx, WT_gcn1, nullptr, nullptr, a1, gcn_b1, bn_gamma, bn_beta,
              nullptr, nullptr, 64, 64, 0, 64, 1};
    p.e[1] = {asagex, WT_sl1, xb, WT_sr1, s1, sage_bl1, nullptr, nullptr,
              nullptr, nullptr, 64, 64, 0, 64, 3};
    for(int hd = 0; hd < 4; hd++)
      p.e[2+hd] = {z + hd*64, WT_gat1, nullptr, nullptr, gath, gat_b1,
                   nullptr, nullptr, nullptr, nullptr, 256, 256, hd*64, 64, 2};
    k_mm_mfma<<<dim3(gN,6), 256, 0, stream>>>(p);
  }

  // ---- GAT layer 2 matmul (K=256) + folded attention dots ----
  {
    MMP p = {};
    p.N = NN;
    p.e[0] = {gath, WT_gat2, nullptr, nullptr, h2, nullptr, gat_as2, gat_ad2,
              asrc2, adst2, 256, 64, 0, 256, 4};
    k_mm_mfma<<<dim3(gN,1), 256, 0, stream>>>(p);
  }

  // ---- layer-2 one-pass pre-aggregation (edge weights inline) ----
  k_aggf<<<g4, 256, 0, stream>>>(a1, s1, h2, asrc2, adst2, dis, invc,
                                 offs, cnt, csr, A2agg, S2agg, T2, NN);

  // ---- final matmuls + gate combine ----
  k_mm_final<<<gN, 256, 0, stream>>>(A2agg, WT_gcn2, gcn_b2, S2agg, WT_sl2, sage_bl2,
                                     s1, WT_sr2, T2, gat_b2, gatew, out, NN);
}

// Round 12
// 377.221 us; speedup vs baseline: 1.0592x; 1.0218x over previous
//
#include <hip/hip_runtime.h>
#include <hip/hip_bf16.h>
#include <math.h>

#define NN 50000
#define NE 400000

typedef __attribute__((ext_vector_type(8))) short bf16x8;
typedef __attribute__((ext_vector_type(4))) float f32x4;

// ---------------- helpers ----------------
__device__ __forceinline__ float lrelu(float v){ return fmaxf(v, 0.2f*v); }
__device__ __forceinline__ float elu1(float v){ return v > 0.f ? v : expm1f(v); }
__device__ __forceinline__ float bflo(unsigned int u){ return __uint_as_float(u << 16); }
__device__ __forceinline__ float bfhi(unsigned int u){ return __uint_as_float(u & 0xffff0000u); }
__device__ __forceinline__ unsigned short f2bf(float f){
  __hip_bfloat16 h = __float2bfloat16(f);
  return *(unsigned short*)&h;
}
__device__ __forceinline__ unsigned int pack2(float lo, float hi){
  return (unsigned int)f2bf(lo) | ((unsigned int)f2bf(hi) << 16);
}

// ---------------- CSR build ----------------
__global__ void k_count(const int* __restrict__ col, int* __restrict__ cnt, int E){
  int e = blockIdx.x*blockDim.x + threadIdx.x;
  if(e < E) atomicAdd(&cnt[col[e]], 1);
}

__global__ void k_alloc(const int* __restrict__ cnt, int* __restrict__ offs,
                        float* __restrict__ dis, float* __restrict__ invc,
                        int* __restrict__ total, int N){
  int i = blockIdx.x*blockDim.x + threadIdx.x;
  int lane = threadIdx.x & 63;
  int v = (i < N) ? cnt[i] : 0;
  int x = v;
  #pragma unroll
  for(int d = 1; d < 64; d <<= 1){ int t = __shfl_up(x, d, 64); if(lane >= d) x += t; }
  int base = 0;
  if(lane == 63 && x > 0) base = atomicAdd(total, x);
  base = __shfl(base, 63, 64);
  if(i < N){
    offs[i] = base + x - v;
    dis[i]  = 1.0f / sqrtf((float)(v + 1));
    invc[i] = 1.0f / fmaxf((float)v, 1.0f);
  }
}

__global__ void k_fill(const int* __restrict__ row, const int* __restrict__ col,
                       const int* __restrict__ offs, int* __restrict__ cursor,
                       int* __restrict__ csr, int E){
  int e = blockIdx.x*blockDim.x + threadIdx.x;
  if(e < E){
    int c = col[e];
    int pos = offs[c] + atomicAdd(&cursor[c], 1);
    csr[pos] = row[e];
  }
}

// ---------------- pack weights -> bf16 transposed WT[col][k] ----------------
struct PKE { const float* W; unsigned short* T; int C, K; };
struct PKP { PKE e[8]; };
__global__ void k_pack(PKP p){
  PKE m = p.e[blockIdx.x];
  int total = m.C * m.K;
  for(int i = threadIdx.x; i < total; i += 256){
    int c = i / m.K, k = i - c*m.K;
    m.T[i] = f2bf(m.W[(size_t)k*m.C + c]);
  }
}

// ---------------- cast x -> bf16 + column sums for gate ----------------
__global__ void k_castsum(const float* __restrict__ x, unsigned short* __restrict__ xb,
                          float* __restrict__ gsum, int N){
  __shared__ float part[4][64];
  int lane = threadIdx.x & 63, w = threadIdx.x >> 6;
  float s = 0.f;
  for(int r = blockIdx.x*4 + w; r < N; r += gridDim.x*4){
    float v = x[(size_t)r*64 + lane];
    xb[(size_t)r*64 + lane] = f2bf(v);
    s += v;
  }
  part[w][lane] = s;
  __syncthreads();
  if(w == 0) atomicAdd(&gsum[lane], part[0][lane]+part[1][lane]+part[2][lane]+part[3][lane]);
}

__global__ void k_gate(const float* __restrict__ gsum,
                       const float* __restrict__ w1, const float* __restrict__ b1,
                       const float* __restrict__ w2, const float* __restrict__ b2,
                       float* __restrict__ gatew){
  __shared__ float g[64]; __shared__ float hid[64]; __shared__ float lg[3];
  int t = threadIdx.x;
  g[t] = gsum[t] * (1.0f/(float)NN);
  __syncthreads();
  float acc = b1[t];
  for(int i = 0; i < 64; i++) acc += g[i]*w1[i*64 + t];
  hid[t] = fmaxf(acc, 0.f);
  __syncthreads();
  if(t < 3){
    float a = b2[t];
    for(int j = 0; j < 64; j++) a += hid[j]*w2[j*3 + t];
    lg[t] = a;
  }
  __syncthreads();
  if(t == 0){
    float m = fmaxf(lg[0], fmaxf(lg[1], lg[2]));
    float e0 = expf(lg[0]-m), e1 = expf(lg[1]-m), e2 = expf(lg[2]-m);
    float s = e0 + e1 + e2;
    gatew[0] = e0/s; gatew[1] = e1/s; gatew[2] = e2/s;
  }
}

// ---------------- fold GAT1 attention vectors through W ----------------
__global__ void k_fold1(const float* __restrict__ w1, const float* __restrict__ as,
                        const float* __restrict__ ad, float* __restrict__ wsd){
  int t = threadIdx.x;            // 256
  int k = t & 63, h = t >> 6;
  float ssrc = 0.f, sdst = 0.f;
  for(int c = 0; c < 64; c++){
    float w = w1[k*256 + h*64 + c];
    ssrc += w * as[h*64 + c];
    sdst += w * ad[h*64 + c];
  }
  wsd[k*8 + h] = ssrc;
  wsd[k*8 + 4 + h] = sdst;
}

// ---------------- asrc1/adst1 = xb @ Wsd  (16 lanes per node) ----------------
__global__ void k_attdotx(const unsigned short* __restrict__ xb, const float* __restrict__ wsd,
                          float* __restrict__ asrc, float* __restrict__ adst, int N){
  __shared__ float ws[64*8];
  int tid = threadIdx.x;
  ws[tid] = wsd[tid];
  ws[tid + 256] = wsd[tid + 256];
  __syncthreads();
  int node = blockIdx.x*16 + (tid >> 4);
  int l = tid & 15;
  if(node >= N) return;
  uint2 u = *(const uint2*)&xb[(size_t)node*64 + l*4];
  float v0 = bflo(u.x), v1 = bfhi(u.x), v2 = bflo(u.y), v3 = bfhi(u.y);
  float s[8];
  #pragma unroll
  for(int h = 0; h < 8; h++){
    s[h] = v0*ws[(l*4+0)*8+h] + v1*ws[(l*4+1)*8+h] + v2*ws[(l*4+2)*8+h] + v3*ws[(l*4+3)*8+h];
  }
  #pragma unroll
  for(int d = 8; d >= 1; d >>= 1){
    #pragma unroll
    for(int h = 0; h < 8; h++) s[h] += __shfl_xor(s[h], d, 16);
  }
  if(l == 0){
    float4 o1; o1.x = s[0]; o1.y = s[1]; o1.z = s[2]; o1.w = s[3];
    float4 o2; o2.x = s[4]; o2.y = s[5]; o2.z = s[6]; o2.w = s[7];
    *(float4*)&asrc[node*4] = o1;
    *(float4*)&adst[node*4] = o2;
  }
}

// ---------------- layer-1 one-pass pre-aggregation over xb ----------------
// Rotation trick: lane subl computes exp for head myh=subl&3 only; other heads via
// __shfl_xor(myw, j). Accumulators kept rotated (zgR[j] = head myh^j); rotation is
// resolved as an address offset at the epilogue.
__global__ void k_aggx(const unsigned short* __restrict__ xb,
                       const float* __restrict__ asrc, const float* __restrict__ adst,
                       const float* __restrict__ dis, const float* __restrict__ invc,
                       const int* __restrict__ offs, const int* __restrict__ cnt,
                       const int* __restrict__ csr,
                       unsigned short* __restrict__ z, unsigned short* __restrict__ agcnx,
                       unsigned short* __restrict__ asagex, int N){
  int node = blockIdx.x*4 + (threadIdx.x >> 6);
  int lane = threadIdx.x & 63;
  if(node >= N) return;
  int half = lane >> 5, subl = lane & 31;      // channels subl*2, subl*2+1
  int myh = subl & 3;
  float adh = adst[node*4 + myh];
  float zgR[4][2] = {{0,0},{0,0},{0,0},{0,0}}; // zgR[j] = head myh^j
  float denR[4] = {0,0,0,0};
  float gg[2] = {0,0}, ssv[2] = {0,0};
  int e0 = offs[node], e1 = e0 + cnt[node];
  for(int e = e0 + half; e < e1; e += 2){
    int s = csr[e];
    float myw = expf(lrelu(asrc[s*4 + myh] + adh));
    float ds = dis[s];
    unsigned int u = *(const unsigned int*)&xb[(size_t)s*64 + subl*2];
    float w1 = __shfl_xor(myw, 1, 64);
    float w2 = __shfl_xor(myw, 2, 64);
    float w3 = __shfl_xor(myw, 3, 64);
    float xl = bflo(u), xh = bfhi(u);
    zgR[0][0] = fmaf(myw, xl, zgR[0][0]); zgR[0][1] = fmaf(myw, xh, zgR[0][1]);
    zgR[1][0] = fmaf(w1,  xl, zgR[1][0]); zgR[1][1] = fmaf(w1,  xh, zgR[1][1]);
    zgR[2][0] = fmaf(w2,  xl, zgR[2][0]); zgR[2][1] = fmaf(w2,  xh, zgR[2][1]);
    zgR[3][0] = fmaf(w3,  xl, zgR[3][0]); zgR[3][1] = fmaf(w3,  xh, zgR[3][1]);
    denR[0] += myw; denR[1] += w1; denR[2] += w2; denR[3] += w3;
    gg[0] = fmaf(ds, xl, gg[0]); gg[1] = fmaf(ds, xh, gg[1]);
    ssv[0] += xl; ssv[1] += xh;
  }
  // combine the two halves (same subl => same myh => same rotation)
  #pragma unroll
  for(int j = 0; j < 4; j++){
    zgR[j][0] += __shfl_xor(zgR[j][0], 32, 64);
    zgR[j][1] += __shfl_xor(zgR[j][1], 32, 64);
    denR[j]   += __shfl_xor(denR[j],   32, 64);
  }
  gg[0] += __shfl_xor(gg[0], 32, 64); gg[1] += __shfl_xor(gg[1], 32, 64);
  ssv[0] += __shfl_xor(ssv[0], 32, 64); ssv[1] += __shfl_xor(ssv[1], 32, 64);
  // self-loop weights, rotated the same way
  float myws = expf(lrelu(asrc[node*4 + myh] + adh));
  float wsR[4];
  wsR[0] = myws;
  wsR[1] = __shfl_xor(myws, 1, 64);
  wsR[2] = __shfl_xor(myws, 2, 64);
  wsR[3] = __shfl_xor(myws, 3, 64);
  if(half == 0){
    unsigned int un = *(const unsigned int*)&xb[(size_t)node*64 + subl*2];
    float xl = bflo(un), xh = bfhi(un);
    unsigned int* zp = (unsigned int*)&z[(size_t)node*256 + subl*2];
    #pragma unroll
    for(int j = 0; j < 4; j++){
      int head = myh ^ j;
      float rd = 1.0f/(denR[j] + wsR[j]);
      zp[head*32] = pack2((zgR[j][0] + wsR[j]*xl)*rd, (zgR[j][1] + wsR[j]*xh)*rd);
    }
    float dc = dis[node], ic = invc[node];
    *(unsigned int*)&agcnx[(size_t)node*64 + subl*2] =
        pack2(dc*fmaf(dc, xl, gg[0]), dc*fmaf(dc, xh, gg[1]));
    *(unsigned int*)&asagex[(size_t)node*64 + subl*2] = pack2(ssv[0]*ic, ssv[1]*ic);
  }
}

// ---------------- layer-2 one-pass pre-aggregation (edge weights inline) ----------------
__global__ void k_aggf(const unsigned short* __restrict__ a1, const unsigned short* __restrict__ s1,
                       const unsigned short* __restrict__ h2,
                       const float* __restrict__ asrc2, const float* __restrict__ adst2,
                       const float* __restrict__ dis, const float* __restrict__ invc,
                       const int* __restrict__ offs, const int* __restrict__ cnt,
                       const int* __restrict__ csr,
                       unsigned short* __restrict__ A2agg, unsigned short* __restrict__ S2agg,
                       unsigned short* __restrict__ T2, int N){
  int node = blockIdx.x*4 + (threadIdx.x >> 6);
  int lane = threadIdx.x & 63;
  if(node >= N) return;
  int half = lane >> 5, subl = lane & 31;
  float ad = adst2[node];
  float aa[2] = {0,0}, ss[2] = {0,0}, tt[2] = {0,0};
  float den = 0.f;
  int e0 = offs[node], e1 = e0 + cnt[node];
  for(int e = e0 + half; e < e1; e += 2){
    int s = csr[e];
    float ds = dis[s];
    float wv = expf(lrelu(asrc2[s] + ad));
    den += wv;
    unsigned int ua = *(const unsigned int*)&a1[(size_t)s*64 + subl*2];
    unsigned int us = *(const unsigned int*)&s1[(size_t)s*64 + subl*2];
    unsigned int uh = *(const unsigned int*)&h2[(size_t)s*64 + subl*2];
    aa[0] = fmaf(ds, bflo(ua), aa[0]); aa[1] = fmaf(ds, bfhi(ua), aa[1]);
    ss[0] += bflo(us); ss[1] += bfhi(us);
    tt[0] = fmaf(wv, bflo(uh), tt[0]); tt[1] = fmaf(wv, bfhi(uh), tt[1]);
  }
  aa[0] += __shfl_xor(aa[0], 32, 64); aa[1] += __shfl_xor(aa[1], 32, 64);
  ss[0] += __shfl_xor(ss[0], 32, 64); ss[1] += __shfl_xor(ss[1], 32, 64);
  tt[0] += __shfl_xor(tt[0], 32, 64); tt[1] += __shfl_xor(tt[1], 32, 64);
  den   += __shfl_xor(den,   32, 64);
  if(half == 0){
    unsigned int uan = *(const unsigned int*)&a1[(size_t)node*64 + subl*2];
    unsigned int uhn = *(const unsigned int*)&h2[(size_t)node*64 + subl*2];
    float dc = dis[node], ic = invc[node];
    float wss = expf(lrelu(asrc2[node] + ad));
    float rd = 1.0f/(den + wss);
    *(unsigned int*)&A2agg[(size_t)node*64 + subl*2] =
        pack2(dc*fmaf(dc, bflo(uan), aa[0]), dc*fmaf(dc, bfhi(uan), aa[1]));
    *(unsigned int*)&S2agg[(size_t)node*64 + subl*2] = pack2(ss[0]*ic, ss[1]*ic);
    *(unsigned int*)&T2[(size_t)node*64 + subl*2] =
        pack2(fmaf(wss, bflo(uhn), tt[0])*rd, fmaf(wss, bfhi(uhn), tt[1])*rd);
  }
}

// ---------------- MFMA bf16 matmul, LDS-free B + coalesced epilogue via LDS tile ----------------
// ep: 1 = BN+relu; 2 = ELU; 3 = sage(+bias, row L2-norm, relu); 4 = plain + att dots
// col0 is the single source of column offset — it indexes WT rows, C columns, and bias.
struct MME {
  const unsigned short* A; const unsigned short* WT;    // WT row stride = K
  const unsigned short* A2; const unsigned short* WT2;  // optional 2nd segment, K2=64
  unsigned short* C;
  const float* b; const float* p1; const float* p2;
  float* y1; float* y2;
  int lda, ldc, col0, K, ep;
};
struct MMP { MME e[6]; int N; };

__global__ __launch_bounds__(256) void k_mm_mfma(MMP p){
  __shared__ unsigned short T[64*72];   // 64-col tile, pitch 72 shorts
  MME m = p.e[blockIdx.y];
  const int N = p.N, K = m.K;
  int tid = threadIdx.x;
  int w = tid >> 6, lane = tid & 63, quad = lane >> 4, m16 = lane & 15;
  int rowa = blockIdx.x*64 + w*16 + m16;
  int rowc = rowa < N ? rowa : N - 1;
  f32x4 acc[4];
  #pragma unroll
  for(int t = 0; t < 4; t++){ acc[t][0]=0.f; acc[t][1]=0.f; acc[t][2]=0.f; acc[t][3]=0.f; }
  for(int kc = 0; kc < K; kc += 64){
    bf16x8 a0 = *(const bf16x8*)&m.A[(size_t)rowc*m.lda + kc + quad*8];
    bf16x8 a1 = *(const bf16x8*)&m.A[(size_t)rowc*m.lda + kc + 32 + quad*8];
    #pragma unroll
    for(int t = 0; t < 4; t++){
      const unsigned short* wr = &m.WT[(size_t)(m.col0 + t*16 + m16)*K + kc + quad*8];
      acc[t] = __builtin_amdgcn_mfma_f32_16x16x32_bf16(a0, *(const bf16x8*)wr, acc[t], 0, 0, 0);
      acc[t] = __builtin_amdgcn_mfma_f32_16x16x32_bf16(a1, *(const bf16x8*)(wr+32), acc[t], 0, 0, 0);
    }
  }
  if(m.A2){
    bf16x8 a0 = *(const bf16x8*)&m.A2[(size_t)rowc*64 + quad*8];
    bf16x8 a1 = *(const bf16x8*)&m.A2[(size_t)rowc*64 + 32 + quad*8];
    #pragma unroll
    for(int t = 0; t < 4; t++){
      const unsigned short* wr = &m.WT2[(size_t)(t*16 + m16)*64 + quad*8];
      acc[t] = __builtin_amdgcn_mfma_f32_16x16x32_bf16(a0, *(const bf16x8*)wr, acc[t], 0, 0, 0);
      acc[t] = __builtin_amdgcn_mfma_f32_16x16x32_bf16(a1, *(const bf16x8*)(wr+32), acc[t], 0, 0, 0);
    }
  }
  if(m.ep == 4){   // attention-dot fold (before tiling)
    float ps[4] = {0,0,0,0}, pd[4] = {0,0,0,0};
    #pragma unroll
    for(int t = 0; t < 4; t++){
      int col = m.col0 + t*16 + m16;
      float a_ = m.p1[col], d_ = m.p2[col];
      #pragma unroll
      for(int r = 0; r < 4; r++){ ps[r] = fmaf(acc[t][r], a_, ps[r]); pd[r] = fmaf(acc[t][r], d_, pd[r]); }
    }
    #pragma unroll
    for(int d = 8; d >= 1; d >>= 1){
      #pragma unroll
      for(int r = 0; r < 4; r++){ ps[r] += __shfl_xor(ps[r], d, 64); pd[r] += __shfl_xor(pd[r], d, 64); }
    }
    if(m16 == 0){
      #pragma unroll
      for(int r = 0; r < 4; r++){
        int ro = blockIdx.x*64 + w*16 + quad*4 + r;
        if(ro < N){ m.y1[ro] = ps[r]; m.y2[ro] = pd[r]; }
      }
    }
  }
  // epilogue -> LDS tile (local 64-col coordinates)
  if(m.ep == 3){
    float v[4][4], n2[4] = {0,0,0,0};
    #pragma unroll
    for(int t = 0; t < 4; t++){
      float bv = m.b[m.col0 + t*16 + m16];
      #pragma unroll
      for(int r = 0; r < 4; r++){ v[t][r] = acc[t][r] + bv; n2[r] = fmaf(v[t][r], v[t][r], n2[r]); }
    }
    #pragma unroll
    for(int d = 8; d >= 1; d >>= 1){
      #pragma unroll
      for(int r = 0; r < 4; r++) n2[r] += __shfl_xor(n2[r], d, 64);
    }
    #pragma unroll
    for(int r = 0; r < 4; r++){
      float inv = 1.0f / fmaxf(sqrtf(n2[r]), 1e-12f);
      int rowl = w*16 + quad*4 + r;
      #pragma unroll
      for(int t = 0; t < 4; t++)
        T[rowl*72 + t*16 + m16] = f2bf(fmaxf(v[t][r]*inv, 0.f));
    }
  } else {
    #pragma unroll
    for(int t = 0; t < 4; t++){
      int col = m.col0 + t*16 + m16;
      float bv = (m.ep == 1 || m.ep == 2) ? m.b[col] : 0.f;
      float gm = (m.ep == 1) ? m.p1[col]*rsqrtf(1.0f + 1e-5f) : 0.f;
      float be = (m.ep == 1) ? m.p2[col] : 0.f;
      #pragma unroll
      for(int r = 0; r < 4; r++){
        int rowl = w*16 + quad*4 + r;
        float val = acc[t][r];
        if(m.ep == 1)      val = fmaxf((val + bv)*gm + be, 0.f);
        else if(m.ep == 2) val = elu1(val + bv);
        T[rowl*72 + t*16 + m16] = f2bf(val);
      }
    }
  }
  __syncthreads();
  int rr = tid >> 2, c0 = (tid & 3)*16;
  int rowg = blockIdx.x*64 + rr;
  if(rowg < N){
    bf16x8 v0 = *(const bf16x8*)&T[rr*72 + c0];
    bf16x8 v1 = *(const bf16x8*)&T[rr*72 + c0 + 8];
    *(bf16x8*)&m.C[(size_t)rowg*m.ldc + m.col0 + c0] = v0;
    *(bf16x8*)&m.C[(size_t)rowg*m.ldc + m.col0 + c0 + 8] = v1;
  }
}

// ---------------- final: GCN2 mm + SAGE2 dual mm + L2norm + GAT2 add + gate combine ----------------
__global__ __launch_bounds__(256) void k_mm_final(
    const unsigned short* __restrict__ A2agg, const unsigned short* __restrict__ WTg,
    const float* __restrict__ gcn_b2,
    const unsigned short* __restrict__ S2agg, const unsigned short* __restrict__ WTl,
    const float* __restrict__ bl2,
    const unsigned short* __restrict__ s1, const unsigned short* __restrict__ WTr,
    const unsigned short* __restrict__ T2, const float* __restrict__ gat_b2,
    const float* __restrict__ gatew, float* __restrict__ out, int N){
  __shared__ float Tf[64*76];
  int tid = threadIdx.x;
  int w = tid >> 6, lane = tid & 63, quad = lane >> 4, m16 = lane & 15;
  int rowa = blockIdx.x*64 + w*16 + m16;
  int rowc = rowa < N ? rowa : N - 1;
  f32x4 accg[4], accs[4];
  #pragma unroll
  for(int t = 0; t < 4; t++){
    accg[t][0]=0.f; accg[t][1]=0.f; accg[t][2]=0.f; accg[t][3]=0.f;
    accs[t][0]=0.f; accs[t][1]=0.f; accs[t][2]=0.f; accs[t][3]=0.f;
  }
  {
    bf16x8 a0 = *(const bf16x8*)&A2agg[(size_t)rowc*64 + quad*8];
    bf16x8 a1 = *(const bf16x8*)&A2agg[(size_t)rowc*64 + 32 + quad*8];
    bf16x8 c0 = *(const bf16x8*)&S2agg[(size_t)rowc*64 + quad*8];
    bf16x8 c1 = *(const bf16x8*)&S2agg[(size_t)rowc*64 + 32 + quad*8];
    bf16x8 d0 = *(const bf16x8*)&s1[(size_t)rowc*64 + quad*8];
    bf16x8 d1 = *(const bf16x8*)&s1[(size_t)rowc*64 + 32 + quad*8];
    #pragma unroll
    for(int t = 0; t < 4; t++){
      const unsigned short* wg = &WTg[(size_t)(t*16 + m16)*64 + quad*8];
      const unsigned short* wl = &WTl[(size_t)(t*16 + m16)*64 + quad*8];
      const unsigned short* wr = &WTr[(size_t)(t*16 + m16)*64 + quad*8];
      accg[t] = __builtin_amdgcn_mfma_f32_16x16x32_bf16(a0, *(const bf16x8*)wg, accg[t], 0, 0, 0);
      accg[t] = __builtin_amdgcn_mfma_f32_16x16x32_bf16(a1, *(const bf16x8*)(wg+32), accg[t], 0, 0, 0);
      accs[t] = __builtin_amdgcn_mfma_f32_16x16x32_bf16(c0, *(const bf16x8*)wl, accs[t], 0, 0, 0);
      accs[t] = __builtin_amdgcn_mfma_f32_16x16x32_bf16(c1, *(const bf16x8*)(wl+32), accs[t], 0, 0, 0);
      accs[t] = __builtin_amdgcn_mfma_f32_16x16x32_bf16(d0, *(const bf16x8*)wr, accs[t], 0, 0, 0);
      accs[t] = __builtin_amdgcn_mfma_f32_16x16x32_bf16(d1, *(const bf16x8*)(wr+32), accs[t], 0, 0, 0);
    }
  }
  float w0 = gatew[0], w1 = gatew[1], w2 = gatew[2];
  float vs[4][4], n2[4] = {0,0,0,0};
  #pragma unroll
  for(int t = 0; t < 4; t++){
    float bsv = bl2[t*16 + m16];
    #pragma unroll
    for(int r = 0; r < 4; r++){ vs[t][r] = accs[t][r] + bsv; n2[r] = fmaf(vs[t][r], vs[t][r], n2[r]); }
  }
  #pragma unroll
  for(int d = 8; d >= 1; d >>= 1){
    #pragma unroll
    for(int r = 0; r < 4; r++) n2[r] += __shfl_xor(n2[r], d, 64);
  }
  #pragma unroll
  for(int r = 0; r < 4; r++){
    float inv = 1.0f / fmaxf(sqrtf(n2[r]), 1e-12f);
    int rowl = w*16 + quad*4 + r;
    int ro = blockIdx.x*64 + rowl;
    int roc = ro < N ? ro : N - 1;
    #pragma unroll
    for(int t = 0; t < 4; t++){
      int col = t*16 + m16;
      float t2 = bflo((unsigned int)T2[(size_t)roc*64 + col]);
      Tf[rowl*76 + col] = w0*(accg[t][r] + gcn_b2[col]) + w1*(t2 + gat_b2[col]) + w2*vs[t][r]*inv;
    }
  }
  __syncthreads();
  int rr = tid >> 2, c0 = (tid & 3)*16;
  int rowg = blockIdx.x*64 + rr;
  if(rowg < N){
    #pragma unroll
    for(int i = 0; i < 4; i++){
      float4 v = *(const float4*)&Tf[rr*76 + c0 + i*4];
      *(float4*)&out[(size_t)rowg*64 + c0 + i*4] = v;
    }
  }
}

// ---------------- host ----------------
extern "C" void kernel_launch(void* const* d_in, const int* in_sizes, int n_in,
                              void* d_out, int out_size, void* d_ws, size_t ws_size,
                              hipStream_t stream){
  const float* x        = (const float*)d_in[0];
  const int*   ei       = (const int*)d_in[1];
  const int*   row      = ei;
  const int*   col      = ei + NE;
  const float* gate_w1  = (const float*)d_in[2];
  const float* gate_b1  = (const float*)d_in[3];
  const float* gate_w2  = (const float*)d_in[4];
  const float* gate_b2  = (const float*)d_in[5];
  const float* gcn_w1   = (const float*)d_in[6];
  const float* gcn_b1   = (const float*)d_in[7];
  const float* bn_gamma = (const float*)d_in[8];
  const float* bn_beta  = (const float*)d_in[9];
  const float* gcn_w2   = (const float*)d_in[10];
  const float* gcn_b2   = (const float*)d_in[11];
  const float* gat_w1   = (const float*)d_in[12];
  const float* gat_as1  = (const float*)d_in[13];
  const float* gat_ad1  = (const float*)d_in[14];
  const float* gat_b1   = (const float*)d_in[15];
  const float* gat_w2   = (const float*)d_in[16];
  const float* gat_as2  = (const float*)d_in[17];
  const float* gat_ad2  = (const float*)d_in[18];
  const float* gat_b2   = (const float*)d_in[19];
  const float* sage_wl1 = (const float*)d_in[20];
  const float* sage_bl1 = (const float*)d_in[21];
  const float* sage_wr1 = (const float*)d_in[22];
  const float* sage_wl2 = (const float*)d_in[23];
  const float* sage_bl2 = (const float*)d_in[24];
  const float* sage_wr2 = (const float*)d_in[25];
  float* out = (float*)d_out;

  char* wp = (char*)d_ws;
  auto alloc = [&](size_t bytes)->char*{ char* p = wp; wp += (bytes + 255) & ~(size_t)255; return p; };
  // zero-init region (contiguous): cnt, cursor, gsum, total
  int*   cnt    = (int*)  alloc((size_t)NN*4);
  int*   cursor = (int*)  alloc((size_t)NN*4);
  float* gsum   = (float*)alloc(64*4);
  int*   total  = (int*)  alloc(256);
  size_t zbytes = (size_t)(wp - (char*)cnt);
  int*   offs   = (int*)  alloc((size_t)NN*4);
  int*   csr    = (int*)  alloc((size_t)NE*4);
  float* dis    = (float*)alloc((size_t)NN*4);
  float* invc   = (float*)alloc((size_t)NN*4);
  float* gatew  = (float*)alloc(16);
  float* wsd    = (float*)alloc(64*8*4);
  float* asrc1  = (float*)alloc((size_t)NN*4*4);
  float* adst1  = (float*)alloc((size_t)NN*4*4);
  float* asrc2  = (float*)alloc((size_t)NN*4);
  float* adst2  = (float*)alloc((size_t)NN*4);
  // packed bf16 transposed weights
  unsigned short* WT_gcn1 = (unsigned short*)alloc(64*64*2);
  unsigned short* WT_sl1  = (unsigned short*)alloc(64*64*2);
  unsigned short* WT_sr1  = (unsigned short*)alloc(64*64*2);
  unsigned short* WT_gat1 = (unsigned short*)alloc(256*64*2);
  unsigned short* WT_gat2 = (unsigned short*)alloc(64*256*2);
  unsigned short* WT_gcn2 = (unsigned short*)alloc(64*64*2);
  unsigned short* WT_sl2  = (unsigned short*)alloc(64*64*2);
  unsigned short* WT_sr2  = (unsigned short*)alloc(64*64*2);
  unsigned short* xb     = (unsigned short*)alloc((size_t)NN*64*2);
  unsigned short* z      = (unsigned short*)alloc((size_t)NN*256*2);
  unsigned short* agcnx  = (unsigned short*)alloc((size_t)NN*64*2);
  unsigned short* asagex = (unsigned short*)alloc((size_t)NN*64*2);
  unsigned short* a1     = (unsigned short*)alloc((size_t)NN*64*2);
  unsigned short* s1     = (unsigned short*)alloc((size_t)NN*64*2);
  unsigned short* gath   = (unsigned short*)alloc((size_t)NN*256*2);
  unsigned short* h2     = (unsigned short*)alloc((size_t)NN*64*2);
  unsigned short* A2agg  = (unsigned short*)alloc((size_t)NN*64*2);
  unsigned short* S2agg  = (unsigned short*)alloc((size_t)NN*64*2);
  unsigned short* T2     = (unsigned short*)alloc((size_t)NN*64*2);

  hipMemsetAsync(cnt, 0, zbytes, stream);

  const int gN  = (NN + 63) / 64;   // 782
  const int g4  = NN / 4;           // 12500
  const int g16 = NN / 16;          // 3125
  const int gA  = (NN + 255) / 256; // 196

  // pack weights (tiny)
  {
    PKP p = {};
    p.e[0] = {gcn_w1,   WT_gcn1, 64,  64};
    p.e[1] = {sage_wl1, WT_sl1,  64,  64};
    p.e[2] = {sage_wr1, WT_sr1,  64,  64};
    p.e[3] = {gat_w1,   WT_gat1, 256, 64};
    p.e[4] = {gat_w2,   WT_gat2, 64,  256};
    p.e[5] = {gcn_w2,   WT_gcn2, 64,  64};
    p.e[6] = {sage_wl2, WT_sl2,  64,  64};
    p.e[7] = {sage_wr2, WT_sr2,  64,  64};
    k_pack<<<8, 256, 0, stream>>>(p);
  }

  k_count<<<(NE+255)/256, 256, 0, stream>>>(col, cnt, NE);
  k_alloc<<<gA, 256, 0, stream>>>(cnt, offs, dis, invc, total, NN);
  k_fill <<<(NE+255)/256, 256, 0, stream>>>(row, col, offs, cursor, csr, NE);
  k_castsum<<<256, 256, 0, stream>>>(x, xb, gsum, NN);
  k_gate  <<<1, 64, 0, stream>>>(gsum, gate_w1, gate_b1, gate_w2, gate_b2, gatew);
  k_fold1 <<<1, 256, 0, stream>>>(gat_w1, gat_as1, gat_ad1, wsd);
  k_attdotx<<<g16, 256, 0, stream>>>(xb, wsd, asrc1, adst1, NN);

  // ---- layer-1 one-pass pre-aggregation (rotation-trick edge weights) ----
  k_aggx<<<g4, 256, 0, stream>>>(xb, asrc1, adst1, dis, invc, offs, cnt, csr,
                                 z, agcnx, asagex, NN);

  // ---- layer-1 matmuls: GCN + SAGE + 4 GAT head slabs, one dispatch ----
  {
    MMP p = {};
    p.N = NN;
    p.e[0] = {agcnx, WT_gcn1, nullptr, nullptr, a1, gcn_b1, bn_gamma, bn_beta,
              nullptr, nullptr, 64, 64, 0, 64, 1};
    p.e[1] = {asagex, WT_sl1, xb, WT_sr1, s1, sage_bl1, nullptr, nullptr,
              nullptr, nullptr, 64, 64, 0, 64, 3};
    for(int hd = 0; hd < 4; hd++)
      p.e[2+hd] = {z + hd*64, WT_gat1, nullptr, nullptr, gath, gat_b1,
                   nullptr, nullptr, nullptr, nullptr, 256, 256, hd*64, 64, 2};
    k_mm_mfma<<<dim3(gN,6), 256, 0, stream>>>(p);
  }

  // ---- GAT layer 2 matmul (K=256) + folded attention dots ----
  {
    MMP p = {};
    p.N = NN;
    p.e[0] = {gath, WT_gat2, nullptr, nullptr, h2, nullptr, gat_as2, gat_ad2,
              asrc2, adst2, 256, 64, 0, 256, 4};
    k_mm_mfma<<<dim3(gN,1), 256, 0, stream>>>(p);
  }

  // ---- layer-2 one-pass pre-aggregation (edge weights inline) ----
  k_aggf<<<g4, 256, 0, stream>>>(a1, s1, h2, asrc2, adst2, dis, invc,
                                 offs, cnt, csr, A2agg, S2agg, T2, NN);

  // ---- final matmuls + gate combine ----
  k_mm_final<<<gN, 256, 0, stream>>>(A2agg, WT_gcn2, gcn_b2, S2agg, WT_sl2, sage_bl2,
                                     s1, WT_sr2, T2, gat_b2, gatew, out, NN);
}